// Round 3
// baseline (273.441 us; speedup 1.0000x reference)
//
#include <hip/hip_runtime.h>
#include <cstddef>

#define EMBED 256
#define HEADS 8
#define LEVELS 4
#define POINTS 4
#define NQOUT 384   // 256 offset outputs + 128 attn logits per query row

// ---------------------------------------------------------------------------
// Generic tiled GEMM: C[M,N] = A[M,K] @ B[N,K]^T + bias[N]
// 64x64 tile, 256 threads, 4x4 micro-tile per thread. Used for the small
// (M=3600) output projection. LDS padded +4 floats -> ds_read_b128 aligned.
// ---------------------------------------------------------------------------
template<int TM, int TN, int TK>
__global__ __launch_bounds__(256) void gemm_abt_bias(
    const float* __restrict__ A, const float* __restrict__ B,
    const float* __restrict__ bias, float* __restrict__ C,
    int M, int N, int K)
{
    __shared__ float As[TK][TM + 4];
    __shared__ float Bs[TK][TN + 4];
    const int tid = threadIdx.x;
    const int m0 = blockIdx.y * TM;
    const int n0 = blockIdx.x * TN;
    const int tx = tid & 15;
    const int ty = tid >> 4;
    const int ar  = tid >> 2;
    const int ac4 = (tid & 3) << 2;

    float acc[4][4] = {};

    for (int k0 = 0; k0 < K; k0 += TK) {
        {
            const int m = m0 + ar;
            float4 va = make_float4(0.f, 0.f, 0.f, 0.f);
            if (m < M) va = *(const float4*)(A + (size_t)m * K + k0 + ac4);
            As[ac4 + 0][ar] = va.x; As[ac4 + 1][ar] = va.y;
            As[ac4 + 2][ar] = va.z; As[ac4 + 3][ar] = va.w;

            const int n = n0 + ar;  // N multiple of TN for our calls
            const float4 vb = *(const float4*)(B + (size_t)n * K + k0 + ac4);
            Bs[ac4 + 0][ar] = vb.x; Bs[ac4 + 1][ar] = vb.y;
            Bs[ac4 + 2][ar] = vb.z; Bs[ac4 + 3][ar] = vb.w;
        }
        __syncthreads();

        #pragma unroll
        for (int k = 0; k < TK; ++k) {
            const float4 a4 = *(const float4*)(&As[k][ty << 2]);
            const float4 b4 = *(const float4*)(&Bs[k][tx << 2]);
            const float a[4] = {a4.x, a4.y, a4.z, a4.w};
            const float b[4] = {b4.x, b4.y, b4.z, b4.w};
            #pragma unroll
            for (int i = 0; i < 4; ++i)
                #pragma unroll
                for (int j = 0; j < 4; ++j)
                    acc[i][j] = fmaf(a[i], b[j], acc[i][j]);
        }
        __syncthreads();
    }

    #pragma unroll
    for (int i = 0; i < 4; ++i) {
        const int m = m0 + (ty << 2) + i;
        if (m >= M) continue;
        #pragma unroll
        for (int j = 0; j < 4; ++j) {
            const int n = n0 + (tx << 2) + j;
            C[(size_t)m * N + n] = acc[i][j] + bias[n];
        }
    }
}

// ---------------------------------------------------------------------------
// Fused query GEMM: C[M,384] = query @ [w_off; w_attn]^T + [b_off; b_attn].
// n-tiles are 64-wide and 256 % 64 == 0, so each block's B-rows come
// entirely from one of the two weight matrices -> uniform pointer select.
// ---------------------------------------------------------------------------
__global__ __launch_bounds__(256) void gemm_query_fused(
    const float* __restrict__ A,
    const float* __restrict__ Boff,  const float* __restrict__ Battn,
    const float* __restrict__ boff,  const float* __restrict__ battn,
    float* __restrict__ C, int M, int K)
{
    constexpr int TM = 64, TN = 64, TK = 16;
    __shared__ float As[TK][TM + 4];
    __shared__ float Bs[TK][TN + 4];
    const int tid = threadIdx.x;
    const int m0 = blockIdx.y * TM;
    const int n0 = blockIdx.x * TN;
    const bool isAttn = (n0 >= 256);
    const float* __restrict__ B  = isAttn ? Battn : Boff;
    const float* __restrict__ bv = isAttn ? battn : boff;
    const int nbase = isAttn ? (n0 - 256) : n0;

    const int tx = tid & 15;
    const int ty = tid >> 4;
    const int ar  = tid >> 2;
    const int ac4 = (tid & 3) << 2;

    float acc[4][4] = {};

    for (int k0 = 0; k0 < K; k0 += TK) {
        {
            const int m = m0 + ar;
            float4 va = make_float4(0.f, 0.f, 0.f, 0.f);
            if (m < M) va = *(const float4*)(A + (size_t)m * K + k0 + ac4);
            As[ac4 + 0][ar] = va.x; As[ac4 + 1][ar] = va.y;
            As[ac4 + 2][ar] = va.z; As[ac4 + 3][ar] = va.w;

            const float4 vb = *(const float4*)(B + (size_t)(nbase + ar) * K + k0 + ac4);
            Bs[ac4 + 0][ar] = vb.x; Bs[ac4 + 1][ar] = vb.y;
            Bs[ac4 + 2][ar] = vb.z; Bs[ac4 + 3][ar] = vb.w;
        }
        __syncthreads();

        #pragma unroll
        for (int k = 0; k < TK; ++k) {
            const float4 a4 = *(const float4*)(&As[k][ty << 2]);
            const float4 b4 = *(const float4*)(&Bs[k][tx << 2]);
            const float a[4] = {a4.x, a4.y, a4.z, a4.w};
            const float b[4] = {b4.x, b4.y, b4.z, b4.w};
            #pragma unroll
            for (int i = 0; i < 4; ++i)
                #pragma unroll
                for (int j = 0; j < 4; ++j)
                    acc[i][j] = fmaf(a[i], b[j], acc[i][j]);
        }
        __syncthreads();
    }

    #pragma unroll
    for (int i = 0; i < 4; ++i) {
        const int m = m0 + (ty << 2) + i;
        if (m >= M) continue;
        #pragma unroll
        for (int j = 0; j < 4; ++j) {
            const int nl = (tx << 2) + j;             // 0..63 within tile
            C[(size_t)m * NQOUT + n0 + nl] = acc[i][j] + bv[nbase + nl];
        }
    }
}

// ---------------------------------------------------------------------------
// Big-M GEMM for the value projection: 128x128 tile, 256 threads, 8x8
// micro-tile. Per k-step: 4 ds_read_b128 vs 64 v_fma_f32 -> LDS issue ~19%
// of FMA cycles, deep FMA ILP.
// ---------------------------------------------------------------------------
template<int TK>
__global__ __launch_bounds__(256) void gemm_abt_bias_128(
    const float* __restrict__ A, const float* __restrict__ B,
    const float* __restrict__ bias, float* __restrict__ C,
    int M, int N, int K)
{
    constexpr int TM = 128, TN = 128;
    __shared__ float As[TK][TM + 4];
    __shared__ float Bs[TK][TN + 4];
    const int tid = threadIdx.x;
    const int m0 = blockIdx.y * TM;
    const int n0 = blockIdx.x * TN;
    const int tx = tid & 15;
    const int ty = tid >> 4;
    const int ar  = tid >> 2;
    const int ac4 = (tid & 3) << 2;

    float acc[8][8] = {};

    for (int k0 = 0; k0 < K; k0 += TK) {
        #pragma unroll
        for (int half = 0; half < 2; ++half) {
            const int r = ar + half * 64;
            const int m = m0 + r;
            float4 va = make_float4(0.f, 0.f, 0.f, 0.f);
            if (m < M) va = *(const float4*)(A + (size_t)m * K + k0 + ac4);
            As[ac4 + 0][r] = va.x; As[ac4 + 1][r] = va.y;
            As[ac4 + 2][r] = va.z; As[ac4 + 3][r] = va.w;

            const int n = n0 + r;   // N multiple of TN for our call
            const float4 vb = *(const float4*)(B + (size_t)n * K + k0 + ac4);
            Bs[ac4 + 0][r] = vb.x; Bs[ac4 + 1][r] = vb.y;
            Bs[ac4 + 2][r] = vb.z; Bs[ac4 + 3][r] = vb.w;
        }
        __syncthreads();

        #pragma unroll
        for (int k = 0; k < TK; ++k) {
            const float4 a0 = *(const float4*)(&As[k][ty << 3]);
            const float4 a1 = *(const float4*)(&As[k][(ty << 3) + 4]);
            const float4 b0 = *(const float4*)(&Bs[k][tx << 3]);
            const float4 b1 = *(const float4*)(&Bs[k][(tx << 3) + 4]);
            const float a[8] = {a0.x, a0.y, a0.z, a0.w, a1.x, a1.y, a1.z, a1.w};
            const float b[8] = {b0.x, b0.y, b0.z, b0.w, b1.x, b1.y, b1.z, b1.w};
            #pragma unroll
            for (int i = 0; i < 8; ++i)
                #pragma unroll
                for (int j = 0; j < 8; ++j)
                    acc[i][j] = fmaf(a[i], b[j], acc[i][j]);
        }
        __syncthreads();
    }

    #pragma unroll
    for (int i = 0; i < 8; ++i) {
        const int m = m0 + (ty << 3) + i;
        if (m >= M) continue;
        const int n = n0 + (tx << 3);
        float4 c0, c1;
        c0.x = acc[i][0] + bias[n + 0]; c0.y = acc[i][1] + bias[n + 1];
        c0.z = acc[i][2] + bias[n + 2]; c0.w = acc[i][3] + bias[n + 3];
        c1.x = acc[i][4] + bias[n + 4]; c1.y = acc[i][5] + bias[n + 5];
        c1.z = acc[i][6] + bias[n + 6]; c1.w = acc[i][7] + bias[n + 7];
        *(float4*)(C + (size_t)m * N + n)     = c0;
        *(float4*)(C + (size_t)m * N + n + 4) = c1;
    }
}

// ---------------------------------------------------------------------------
// Deformable sampling with fused 16-way softmax.
// One block per (b,q); 256 threads = 8 heads x 32 dims.
// qout row layout: [0..255] = offsets (h,l,p,2), [256..383] = attn logits.
// Replicates grid_sample(align_corners=False, padding_mode='zeros').
// ---------------------------------------------------------------------------
__global__ __launch_bounds__(256) void ms_sample_kernel(
    const float* __restrict__ vproj,   // [bs, Lv, 256]
    const float* __restrict__ refp,    // [bs, Lq, 4, 2]
    const float* __restrict__ qout,    // [bs, Lq, 384]
    const int*   __restrict__ shapes,  // [4][2] = (H, W)
    const int*   __restrict__ startix, // [4]
    float* __restrict__ sampled,       // [bs, Lq, 256]
    int Lq, int Lv)
{
    __shared__ float aw_lds[HEADS * LEVELS * POINTS];   // 128 softmaxed weights

    const int bq = blockIdx.x;
    const int b  = bq / Lq;
    const int tid = threadIdx.x;
    const int h = tid >> 5, d = tid & 31;

    const float* vb   = vproj + (size_t)b * Lv * EMBED;
    const float* rowq = qout + (size_t)bq * NQOUT;
    const float* offq = rowq;                 // 256 offsets
    const float* logq = rowq + 256;           // 128 logits
    const float* refq = refp + (size_t)bq * LEVELS * 2;

    // --- fused softmax over each head's 16 logits (threads 0..127) ---
    if (tid < HEADS * LEVELS * POINTS) {
        const float v = logq[tid];
        float m = v;
        #pragma unroll
        for (int s = 8; s > 0; s >>= 1) m = fmaxf(m, __shfl_xor(m, s, 16));
        const float e = __expf(v - m);
        float sum = e;
        #pragma unroll
        for (int s = 8; s > 0; s >>= 1) sum += __shfl_xor(sum, s, 16);
        aw_lds[tid] = e / sum;
    }
    __syncthreads();

    float accv = 0.f;
    #pragma unroll
    for (int l = 0; l < LEVELS; ++l) {
        const int H = shapes[l * 2 + 0];
        const int W = shapes[l * 2 + 1];
        const int st = startix[l];
        const float fW = (float)W, fH = (float)H;
        const float rx = refq[l * 2 + 0];
        const float ry = refq[l * 2 + 1];
        #pragma unroll
        for (int p = 0; p < POINTS; ++p) {
            const int oi = (((h * LEVELS + l) * POINTS) + p) * 2;
            const float ox = offq[oi + 0];
            const float oy = offq[oi + 1];
            const float aw = aw_lds[(h * LEVELS + l) * POINTS + p];
            // match reference fp exactly: loc = ref + off/norm; x = loc*W - 0.5
            const float x = (rx + ox / fW) * fW - 0.5f;
            const float y = (ry + oy / fH) * fH - 0.5f;
            const float x0f = floorf(x), y0f = floorf(y);
            const float lx = x - x0f, ly = y - y0f;
            const int x0 = (int)x0f, y0 = (int)y0f;
            float s = 0.f;
            #pragma unroll
            for (int c = 0; c < 4; ++c) {
                const int xi = x0 + (c & 1);
                const int yi = y0 + (c >> 1);
                const float wx = (c & 1) ? lx : 1.f - lx;
                const float wy = (c >> 1) ? ly : 1.f - ly;
                const bool valid = (xi >= 0) && (xi < W) && (yi >= 0) && (yi < H);
                const int xc = min(max(xi, 0), W - 1);
                const int yc = min(max(yi, 0), H - 1);
                const float val = vb[(size_t)(st + yc * W + xc) * EMBED + (h << 5) + d];
                s = fmaf(valid ? wx * wy : 0.f, val, s);
            }
            accv = fmaf(aw, s, accv);
        }
    }
    sampled[(size_t)bq * EMBED + tid] = accv;
}

// ---------------------------------------------------------------------------
extern "C" void kernel_launch(void* const* d_in, const int* in_sizes, int n_in,
                              void* d_out, int out_size, void* d_ws, size_t ws_size,
                              hipStream_t stream)
{
    const float* query   = (const float*)d_in[0];
    const float* refp    = (const float*)d_in[1];
    const float* value   = (const float*)d_in[2];
    const int*   shapes  = (const int*)d_in[3];
    const int*   startix = (const int*)d_in[4];
    const float* w_value = (const float*)d_in[5];
    const float* b_value = (const float*)d_in[6];
    const float* w_off   = (const float*)d_in[7];
    const float* b_off   = (const float*)d_in[8];
    const float* w_attn  = (const float*)d_in[9];
    const float* b_attn  = (const float*)d_in[10];
    const float* w_out   = (const float*)d_in[11];
    const float* b_out   = (const float*)d_in[12];
    float* out = (float*)d_out;

    const int bs = 4;
    const int Lq = in_sizes[0] / (bs * EMBED);   // 900
    const int Lv = in_sizes[2] / (bs * EMBED);   // 13294
    const int BQ = bs * Lq;                      // 3600

    float* ws = (float*)d_ws;
    float* vproj   = ws; ws += (size_t)bs * Lv * EMBED;  // 54.5 MB
    float* qoutb   = ws; ws += (size_t)BQ * NQOUT;       // 5.5 MB
    float* sampled = ws; ws += (size_t)BQ * EMBED;       // 3.7 MB

    // 1. value projection: [bs*Lv,256] @ w_value.T  (dominant GEMM, 128-tile)
    {
        const int M = bs * Lv;
        dim3 grid(EMBED / 128, (M + 127) / 128);
        hipLaunchKernelGGL((gemm_abt_bias_128<16>), grid, dim3(256), 0, stream,
                           value, w_value, b_value, vproj, M, EMBED, EMBED);
    }
    // 2. fused query GEMM: offsets (N=256) + attn logits (N=128) in one pass
    {
        dim3 grid(NQOUT / 64, (BQ + 63) / 64);
        hipLaunchKernelGGL(gemm_query_fused, grid, dim3(256), 0, stream,
                           query, w_off, w_attn, b_off, b_attn, qoutb, BQ, EMBED);
    }
    // 3. deformable sampling with fused softmax
    {
        hipLaunchKernelGGL(ms_sample_kernel, dim3(BQ), dim3(256), 0, stream,
                           vproj, refp, qoutb, shapes, startix, sampled, Lq, Lv);
    }
    // 4. output projection: [BQ,256] @ w_out.T -> d_out
    {
        dim3 grid(EMBED / 64, (BQ + 63) / 64);
        hipLaunchKernelGGL((gemm_abt_bias<64, 64, 16>), grid, dim3(256), 0, stream,
                           sampled, w_out, b_out, out, BQ, EMBED, EMBED);
    }
}

// Round 5
// 226.087 us; speedup vs baseline: 1.2094x; 1.2094x over previous
//
#include <hip/hip_runtime.h>
#include <cstddef>

#define EMBED 256
#define HEADS 8
#define LEVELS 4
#define POINTS 4
#define NQOUT 384   // 256 offset outputs + 128 attn logits per query row

typedef __attribute__((ext_vector_type(8))) short bf16x8;
typedef __attribute__((ext_vector_type(4))) float f32x4;

__device__ __forceinline__ unsigned short bf16_rn(float x) {
    union { float f; unsigned u; } v; v.f = x;
    const unsigned r = v.u + 0x7fffu + ((v.u >> 16) & 1u);
    return (unsigned short)(r >> 16);
}
__device__ __forceinline__ float bf16_to_f(unsigned short h) {
    union { unsigned u; float f; } v; v.u = (unsigned)h << 16;
    return v.f;
}

// ---------------------------------------------------------------------------
// Value projection via bf16-split MFMA: C[M,256] = A[M,256] @ B[256,256]^T + bias.
// A = Ah + Al (bf16 hi/lo), likewise B; C ~= Ah*Bh + Ah*Bl + Al*Bh (drop Al*Bl,
// rel err ~2^-16). 128x128 tile, BK=32, 4 waves in 2x2, each wave 64x64 out
// (4x4 fragments of 16x16x32). LDS rows XOR-swizzled (byte ^= (row&7)<<4):
// bijective, and fragment ds_read_b128 becomes bank-balanced (8 x 4B/bank).
// ---------------------------------------------------------------------------
__global__ __launch_bounds__(256) void gemm_mfma_split(
    const float* __restrict__ A, const float* __restrict__ B,
    const float* __restrict__ bias, float* __restrict__ C, int M)
{
    __shared__ unsigned short AsH[128 * 32], AsL[128 * 32];
    __shared__ unsigned short BsH[128 * 32], BsL[128 * 32];

    const int tid  = threadIdx.x;
    const int lane = tid & 63;
    const int wid  = tid >> 6;
    const int wm   = (wid >> 1) * 64;   // wave row offset in tile
    const int wn   = (wid & 1) * 64;    // wave col offset in tile
    const int m0   = blockIdx.y * 128;
    const int n0   = blockIdx.x * 128;

    // staging role: thread -> one LDS row, 16 consecutive floats (4 float4)
    const int sr = tid >> 1;            // 0..127
    const int sc = (tid & 1) * 16;      // float offset in row: 0 or 16

    const bool mok = (m0 + sr) < M;
    const float* ga = A + (size_t)(m0 + sr) * 256 + sc;
    const float* gb = B + (size_t)(n0 + sr) * 256 + sc;

    f32x4 acc[4][4] = {};

    for (int k0 = 0; k0 < 256; k0 += 32) {
        // ---- stage + convert fp32 -> bf16 hi/lo, swizzled LDS writes ----
        #pragma unroll
        for (int i = 0; i < 4; ++i) {
            const int byte_in_row = (sc + i * 4) * 2;              // 4 bf16 = 8B
            int addr = sr * 64 + byte_in_row;
            addr ^= (sr & 7) << 4;

            float4 va = make_float4(0.f, 0.f, 0.f, 0.f);
            if (mok) va = *(const float4*)(ga + k0 + i * 4);
            const unsigned short ah0 = bf16_rn(va.x), ah1 = bf16_rn(va.y);
            const unsigned short ah2 = bf16_rn(va.z), ah3 = bf16_rn(va.w);
            const unsigned short al0 = bf16_rn(va.x - bf16_to_f(ah0));
            const unsigned short al1 = bf16_rn(va.y - bf16_to_f(ah1));
            const unsigned short al2 = bf16_rn(va.z - bf16_to_f(ah2));
            const unsigned short al3 = bf16_rn(va.w - bf16_to_f(ah3));
            *(uint2*)((char*)AsH + addr) =
                make_uint2((unsigned)ah0 | ((unsigned)ah1 << 16),
                           (unsigned)ah2 | ((unsigned)ah3 << 16));
            *(uint2*)((char*)AsL + addr) =
                make_uint2((unsigned)al0 | ((unsigned)al1 << 16),
                           (unsigned)al2 | ((unsigned)al3 << 16));

            const float4 vb = *(const float4*)(gb + k0 + i * 4);
            const unsigned short bh0 = bf16_rn(vb.x), bh1 = bf16_rn(vb.y);
            const unsigned short bh2 = bf16_rn(vb.z), bh3 = bf16_rn(vb.w);
            const unsigned short bl0 = bf16_rn(vb.x - bf16_to_f(bh0));
            const unsigned short bl1 = bf16_rn(vb.y - bf16_to_f(bh1));
            const unsigned short bl2 = bf16_rn(vb.z - bf16_to_f(bh2));
            const unsigned short bl3 = bf16_rn(vb.w - bf16_to_f(bh3));
            *(uint2*)((char*)BsH + addr) =
                make_uint2((unsigned)bh0 | ((unsigned)bh1 << 16),
                           (unsigned)bh2 | ((unsigned)bh3 << 16));
            *(uint2*)((char*)BsL + addr) =
                make_uint2((unsigned)bl0 | ((unsigned)bl1 << 16),
                           (unsigned)bl2 | ((unsigned)bl3 << 16));
        }
        __syncthreads();

        // ---- fragment loads (swizzled) + 48 MFMAs ----
        bf16x8 ah[4], al[4], bh[4], bl[4];
        const int kb = (lane >> 4) * 16;     // byte offset of this lane's k-chunk
        #pragma unroll
        for (int f = 0; f < 4; ++f) {
            const int rowA = wm + f * 16 + (lane & 15);
            int aaddr = rowA * 64 + kb;  aaddr ^= (rowA & 7) << 4;
            ah[f] = *(const bf16x8*)((const char*)AsH + aaddr);
            al[f] = *(const bf16x8*)((const char*)AsL + aaddr);
            const int rowB = wn + f * 16 + (lane & 15);
            int baddr = rowB * 64 + kb;  baddr ^= (rowB & 7) << 4;
            bh[f] = *(const bf16x8*)((const char*)BsH + baddr);
            bl[f] = *(const bf16x8*)((const char*)BsL + baddr);
        }
        #pragma unroll
        for (int mi = 0; mi < 4; ++mi)
            #pragma unroll
            for (int ni = 0; ni < 4; ++ni) {
                acc[mi][ni] = __builtin_amdgcn_mfma_f32_16x16x32_bf16(
                    ah[mi], bh[ni], acc[mi][ni], 0, 0, 0);
                acc[mi][ni] = __builtin_amdgcn_mfma_f32_16x16x32_bf16(
                    ah[mi], bl[ni], acc[mi][ni], 0, 0, 0);
                acc[mi][ni] = __builtin_amdgcn_mfma_f32_16x16x32_bf16(
                    al[mi], bh[ni], acc[mi][ni], 0, 0, 0);
            }
        __syncthreads();
    }

    // ---- epilogue: C/D layout col=lane&15, row=(lane>>4)*4+reg (m89) ----
    #pragma unroll
    for (int mi = 0; mi < 4; ++mi) {
        #pragma unroll
        for (int j = 0; j < 4; ++j) {
            const int m = m0 + wm + mi * 16 + ((lane >> 4) << 2) + j;
            if (m >= M) continue;
            #pragma unroll
            for (int ni = 0; ni < 4; ++ni) {
                const int n = n0 + wn + ni * 16 + (lane & 15);
                C[(size_t)m * 256 + n] = acc[mi][ni][j] + bias[n];
            }
        }
    }
}

// ---------------------------------------------------------------------------
// Generic tiled GEMM: C[M,N] = A[M,K] @ B[N,K]^T + bias[N]
// 64x64 tile, 256 threads, 4x4 micro-tile. B-read slot = tx -> 2-way only.
// ---------------------------------------------------------------------------
template<int TM, int TN, int TK>
__global__ __launch_bounds__(256) void gemm_abt_bias(
    const float* __restrict__ A, const float* __restrict__ B,
    const float* __restrict__ bias, float* __restrict__ C,
    int M, int N, int K)
{
    __shared__ float As[TK][TM + 4];
    __shared__ float Bs[TK][TN + 4];
    const int tid = threadIdx.x;
    const int m0 = blockIdx.y * TM;
    const int n0 = blockIdx.x * TN;
    const int tx = tid & 15;
    const int ty = tid >> 4;
    const int ar  = tid >> 2;
    const int ac4 = (tid & 3) << 2;

    float acc[4][4] = {};

    for (int k0 = 0; k0 < K; k0 += TK) {
        {
            const int m = m0 + ar;
            float4 va = make_float4(0.f, 0.f, 0.f, 0.f);
            if (m < M) va = *(const float4*)(A + (size_t)m * K + k0 + ac4);
            As[ac4 + 0][ar] = va.x; As[ac4 + 1][ar] = va.y;
            As[ac4 + 2][ar] = va.z; As[ac4 + 3][ar] = va.w;

            const int n = n0 + ar;
            const float4 vb = *(const float4*)(B + (size_t)n * K + k0 + ac4);
            Bs[ac4 + 0][ar] = vb.x; Bs[ac4 + 1][ar] = vb.y;
            Bs[ac4 + 2][ar] = vb.z; Bs[ac4 + 3][ar] = vb.w;
        }
        __syncthreads();

        #pragma unroll
        for (int k = 0; k < TK; ++k) {
            const float4 a4 = *(const float4*)(&As[k][ty << 2]);
            const float4 b4 = *(const float4*)(&Bs[k][tx << 2]);
            const float a[4] = {a4.x, a4.y, a4.z, a4.w};
            const float b[4] = {b4.x, b4.y, b4.z, b4.w};
            #pragma unroll
            for (int i = 0; i < 4; ++i)
                #pragma unroll
                for (int j = 0; j < 4; ++j)
                    acc[i][j] = fmaf(a[i], b[j], acc[i][j]);
        }
        __syncthreads();
    }

    #pragma unroll
    for (int i = 0; i < 4; ++i) {
        const int m = m0 + (ty << 2) + i;
        if (m >= M) continue;
        #pragma unroll
        for (int j = 0; j < 4; ++j) {
            const int n = n0 + (tx << 2) + j;
            C[(size_t)m * N + n] = acc[i][j] + bias[n];
        }
    }
}

// ---------------------------------------------------------------------------
// Fused query GEMM: C[M,384] = query @ [w_off; w_attn]^T + [b_off; b_attn].
// ---------------------------------------------------------------------------
__global__ __launch_bounds__(256) void gemm_query_fused(
    const float* __restrict__ A,
    const float* __restrict__ Boff,  const float* __restrict__ Battn,
    const float* __restrict__ boff,  const float* __restrict__ battn,
    float* __restrict__ C, int M, int K)
{
    constexpr int TM = 64, TN = 64, TK = 16;
    __shared__ float As[TK][TM + 4];
    __shared__ float Bs[TK][TN + 4];
    const int tid = threadIdx.x;
    const int m0 = blockIdx.y * TM;
    const int n0 = blockIdx.x * TN;
    const bool isAttn = (n0 >= 256);
    const float* __restrict__ B  = isAttn ? Battn : Boff;
    const float* __restrict__ bv = isAttn ? battn : boff;
    const int nbase = isAttn ? (n0 - 256) : n0;

    const int tx = tid & 15;
    const int ty = tid >> 4;
    const int ar  = tid >> 2;
    const int ac4 = (tid & 3) << 2;

    float acc[4][4] = {};

    for (int k0 = 0; k0 < K; k0 += TK) {
        {
            const int m = m0 + ar;
            float4 va = make_float4(0.f, 0.f, 0.f, 0.f);
            if (m < M) va = *(const float4*)(A + (size_t)m * K + k0 + ac4);
            As[ac4 + 0][ar] = va.x; As[ac4 + 1][ar] = va.y;
            As[ac4 + 2][ar] = va.z; As[ac4 + 3][ar] = va.w;

            const float4 vb = *(const float4*)(B + (size_t)(nbase + ar) * K + k0 + ac4);
            Bs[ac4 + 0][ar] = vb.x; Bs[ac4 + 1][ar] = vb.y;
            Bs[ac4 + 2][ar] = vb.z; Bs[ac4 + 3][ar] = vb.w;
        }
        __syncthreads();

        #pragma unroll
        for (int k = 0; k < TK; ++k) {
            const float4 a4 = *(const float4*)(&As[k][ty << 2]);
            const float4 b4 = *(const float4*)(&Bs[k][tx << 2]);
            const float a[4] = {a4.x, a4.y, a4.z, a4.w};
            const float b[4] = {b4.x, b4.y, b4.z, b4.w};
            #pragma unroll
            for (int i = 0; i < 4; ++i)
                #pragma unroll
                for (int j = 0; j < 4; ++j)
                    acc[i][j] = fmaf(a[i], b[j], acc[i][j]);
        }
        __syncthreads();
    }

    #pragma unroll
    for (int i = 0; i < 4; ++i) {
        const int m = m0 + (ty << 2) + i;
        if (m >= M) continue;
        #pragma unroll
        for (int j = 0; j < 4; ++j) {
            const int nl = (tx << 2) + j;
            C[(size_t)m * NQOUT + n0 + nl] = acc[i][j] + bv[nbase + nl];
        }
    }
}

// ---------------------------------------------------------------------------
// Deformable sampling with fused 16-way softmax.
// ---------------------------------------------------------------------------
__global__ __launch_bounds__(256) void ms_sample_kernel(
    const float* __restrict__ vproj,   // [bs, Lv, 256]
    const float* __restrict__ refp,    // [bs, Lq, 4, 2]
    const float* __restrict__ qout,    // [bs, Lq, 384]
    const int*   __restrict__ shapes,  // [4][2] = (H, W)
    const int*   __restrict__ startix, // [4]
    float* __restrict__ sampled,       // [bs, Lq, 256]
    int Lq, int Lv)
{
    __shared__ float aw_lds[HEADS * LEVELS * POINTS];

    const int bq = blockIdx.x;
    const int b  = bq / Lq;
    const int tid = threadIdx.x;
    const int h = tid >> 5, d = tid & 31;

    const float* vb   = vproj + (size_t)b * Lv * EMBED;
    const float* rowq = qout + (size_t)bq * NQOUT;
    const float* offq = rowq;
    const float* logq = rowq + 256;
    const float* refq = refp + (size_t)bq * LEVELS * 2;

    if (tid < HEADS * LEVELS * POINTS) {
        const float v = logq[tid];
        float m = v;
        #pragma unroll
        for (int s = 8; s > 0; s >>= 1) m = fmaxf(m, __shfl_xor(m, s, 16));
        const float e = __expf(v - m);
        float sum = e;
        #pragma unroll
        for (int s = 8; s > 0; s >>= 1) sum += __shfl_xor(sum, s, 16);
        aw_lds[tid] = e / sum;
    }
    __syncthreads();

    float accv = 0.f;
    #pragma unroll
    for (int l = 0; l < LEVELS; ++l) {
        const int H = shapes[l * 2 + 0];
        const int W = shapes[l * 2 + 1];
        const int st = startix[l];
        const float fW = (float)W, fH = (float)H;
        const float rx = refq[l * 2 + 0];
        const float ry = refq[l * 2 + 1];
        #pragma unroll
        for (int p = 0; p < POINTS; ++p) {
            const int oi = (((h * LEVELS + l) * POINTS) + p) * 2;
            const float ox = offq[oi + 0];
            const float oy = offq[oi + 1];
            const float aw = aw_lds[(h * LEVELS + l) * POINTS + p];
            const float x = (rx + ox / fW) * fW - 0.5f;
            const float y = (ry + oy / fH) * fH - 0.5f;
            const float x0f = floorf(x), y0f = floorf(y);
            const float lx = x - x0f, ly = y - y0f;
            const int x0 = (int)x0f, y0 = (int)y0f;
            float s = 0.f;
            #pragma unroll
            for (int c = 0; c < 4; ++c) {
                const int xi = x0 + (c & 1);
                const int yi = y0 + (c >> 1);
                const float wx = (c & 1) ? lx : 1.f - lx;
                const float wy = (c >> 1) ? ly : 1.f - ly;
                const bool valid = (xi >= 0) && (xi < W) && (yi >= 0) && (yi < H);
                const int xc = min(max(xi, 0), W - 1);
                const int yc = min(max(yi, 0), H - 1);
                const float val = vb[(size_t)(st + yc * W + xc) * EMBED + (h << 5) + d];
                s = fmaf(valid ? wx * wy : 0.f, val, s);
            }
            accv = fmaf(aw, s, accv);
        }
    }
    sampled[(size_t)bq * EMBED + tid] = accv;
}

// ---------------------------------------------------------------------------
extern "C" void kernel_launch(void* const* d_in, const int* in_sizes, int n_in,
                              void* d_out, int out_size, void* d_ws, size_t ws_size,
                              hipStream_t stream)
{
    const float* query   = (const float*)d_in[0];
    const float* refp    = (const float*)d_in[1];
    const float* value   = (const float*)d_in[2];
    const int*   shapes  = (const int*)d_in[3];
    const int*   startix = (const int*)d_in[4];
    const float* w_value = (const float*)d_in[5];
    const float* b_value = (const float*)d_in[6];
    const float* w_off   = (const float*)d_in[7];
    const float* b_off   = (const float*)d_in[8];
    const float* w_attn  = (const float*)d_in[9];
    const float* b_attn  = (const float*)d_in[10];
    const float* w_out   = (const float*)d_in[11];
    const float* b_out   = (const float*)d_in[12];
    float* out = (float*)d_out;

    const int bs = 4;
    const int Lq = in_sizes[0] / (bs * EMBED);   // 900
    const int Lv = in_sizes[2] / (bs * EMBED);   // 13294
    const int BQ = bs * Lq;                      // 3600

    float* ws = (float*)d_ws;
    float* vproj   = ws; ws += (size_t)bs * Lv * EMBED;  // 54.5 MB
    float* qoutb   = ws; ws += (size_t)BQ * NQOUT;       // 5.5 MB
    float* sampled = ws; ws += (size_t)BQ * EMBED;       // 3.7 MB

    // 1. value projection via bf16-split MFMA
    {
        const int M = bs * Lv;
        dim3 grid(EMBED / 128, (M + 127) / 128);
        hipLaunchKernelGGL(gemm_mfma_split, grid, dim3(256), 0, stream,
                           value, w_value, b_value, vproj, M);
    }
    // 2. fused query GEMM: offsets (N=256) + attn logits (N=128)
    {
        dim3 grid(NQOUT / 64, (BQ + 63) / 64);
        hipLaunchKernelGGL(gemm_query_fused, grid, dim3(256), 0, stream,
                           query, w_off, w_attn, b_off, b_attn, qoutb, BQ, EMBED);
    }
    // 3. deformable sampling with fused softmax
    {
        hipLaunchKernelGGL(ms_sample_kernel, dim3(BQ), dim3(256), 0, stream,
                           vproj, refp, qoutb, shapes, startix, sampled, Lq, Lv);
    }
    // 4. output projection: [BQ,256] @ w_out.T -> d_out
    {
        dim3 grid(EMBED / 64, (BQ + 63) / 64);
        hipLaunchKernelGGL((gemm_abt_bias<64, 64, 16>), grid, dim3(256), 0, stream,
                           sampled, w_out, b_out, out, BQ, EMBED, EMBED);
    }
}

// Round 8
// 221.657 us; speedup vs baseline: 1.2336x; 1.0200x over previous
//
#include <hip/hip_runtime.h>
#include <cstddef>

#define EMBED 256
#define HEADS 8
#define LEVELS 4
#define POINTS 4
#define NQOUT 384   // 256 offset outputs + 128 attn logits per query row

typedef __attribute__((ext_vector_type(8))) short bf16x8;
typedef __attribute__((ext_vector_type(4))) float f32x4;

__device__ __forceinline__ unsigned short bf16_rn(float x) {
    union { float f; unsigned u; } v; v.f = x;
    const unsigned r = v.u + 0x7fffu + ((v.u >> 16) & 1u);
    return (unsigned short)(r >> 16);
}
__device__ __forceinline__ float bf16_to_f(unsigned short h) {
    union { unsigned u; float f; } v; v.u = (unsigned)h << 16;
    return v.f;
}
// swizzled byte offset within a [rows][32]-bf16 tile of 64B rows (T2/G4 fix)
__device__ __forceinline__ int sw_addr(int row, int byte_in_row) {
    return (row * 64 + byte_in_row) ^ ((row & 7) << 4);
}

// ---------------------------------------------------------------------------
// Prep: convert w_value [256x256] fp32 -> hi/lo bf16 images laid out exactly
// as the GEMM's swizzled LDS B-tiles: img[kp][sw_addr(r, kk*2)], kp = k/32.
// The GEMM then stages B with global_load_lds (byte-identical image copy).
// 2048 threads, one (row, k-panel) pair each.
// ---------------------------------------------------------------------------
__global__ __launch_bounds__(256) void prep_w(
    const float* __restrict__ w,
    unsigned short* __restrict__ hi, unsigned short* __restrict__ lo)
{
    const int t  = blockIdx.x * 256 + threadIdx.x;   // 0..2047
    const int r  = t >> 3;
    const int kp = t & 7;
    const float* src = w + (size_t)r * 256 + kp * 32;
    #pragma unroll
    for (int c = 0; c < 4; ++c) {                    // 4 chunks of 8 elems (16B)
        unsigned hw[4], lw[4];
        #pragma unroll
        for (int j = 0; j < 4; ++j) {
            const float f0 = src[c * 8 + j * 2 + 0];
            const float f1 = src[c * 8 + j * 2 + 1];
            const unsigned short h0 = bf16_rn(f0), h1 = bf16_rn(f1);
            const unsigned short l0 = bf16_rn(f0 - bf16_to_f(h0));
            const unsigned short l1 = bf16_rn(f1 - bf16_to_f(h1));
            hw[j] = (unsigned)h0 | ((unsigned)h1 << 16);
            lw[j] = (unsigned)l0 | ((unsigned)l1 << 16);
        }
        const int addr = kp * 16384 + sw_addr(r, c * 16);
        *(uint4*)((char*)hi + addr) = make_uint4(hw[0], hw[1], hw[2], hw[3]);
        *(uint4*)((char*)lo + addr) = make_uint4(lw[0], lw[1], lw[2], lw[3]);
    }
}

// ---------------------------------------------------------------------------
// Value projection via bf16-split MFMA, v2.
// C[M,256] = A[M,256] @ B[256,256]^T + bias;  A,B split hi/lo bf16,
// C ~= Ah*Bh + Ah*Bl + Al*Bh. Tile 64(M) x 256(N), BK=32, 4 waves side by
// side (each 64x64 out, 4x4 frags of 16x16x32). grid.x == 1 -> A converted
// exactly once; B staged from pre-swizzled images via global_load_lds
// (width 16, zero staging VALU). LDS 40KB -> ~4 blocks/CU.
// ---------------------------------------------------------------------------
__global__ __launch_bounds__(256) void vproj_mfma(
    const float* __restrict__ A,
    const unsigned short* __restrict__ Bhi, const unsigned short* __restrict__ Blo,
    const float* __restrict__ bias, float* __restrict__ C, int M)
{
    __shared__ unsigned short AsH[64 * 32], AsL[64 * 32];      // 4KB each
    __shared__ unsigned short BsH[256 * 32], BsL[256 * 32];    // 16KB each

    const int tid  = threadIdx.x;
    const int lane = tid & 63;
    const int wn   = (tid >> 6) * 64;        // wave col offset (0,64,128,192)
    const int m0   = blockIdx.x * 64;

    // A staging role: row sr, 8 floats starting at sc
    const int sr = tid >> 2;                 // 0..63
    const int sc = (tid & 3) * 8;            // 0,8,16,24
    const bool mok = (m0 + sr) < M;
    const float* ga = A + (size_t)(m0 + sr) * 256 + sc;

    // B staging: byte-identical image copy, lds dest = wave base + lane*16
    const int wbase = (tid & 192) * 16;      // wid*1024

    f32x4 acc[4][4] = {};

    for (int kp = 0; kp < 8; ++kp) {
        // ---- issue B panel loads first (latency hides under A convert) ----
        #pragma unroll
        for (int i = 0; i < 4; ++i) {
            const int off = i * 4096 + wbase + (lane << 4);
            __builtin_amdgcn_global_load_lds(
                (const __attribute__((address_space(1))) unsigned int*)
                    ((const char*)Bhi + kp * 16384 + off),
                (__attribute__((address_space(3))) unsigned int*)
                    ((char*)BsH + i * 4096 + wbase),
                16, 0, 0);
            __builtin_amdgcn_global_load_lds(
                (const __attribute__((address_space(1))) unsigned int*)
                    ((const char*)Blo + kp * 16384 + off),
                (__attribute__((address_space(3))) unsigned int*)
                    ((char*)BsL + i * 4096 + wbase),
                16, 0, 0);
        }

        // ---- stage A: fp32 -> bf16 hi/lo, swizzled ds_write (8 elems) ----
        #pragma unroll
        for (int q = 0; q < 2; ++q) {
            float4 va = make_float4(0.f, 0.f, 0.f, 0.f);
            if (mok) va = *(const float4*)(ga + kp * 32 + q * 4);
            const unsigned short h0 = bf16_rn(va.x), h1 = bf16_rn(va.y);
            const unsigned short h2 = bf16_rn(va.z), h3 = bf16_rn(va.w);
            const unsigned short l0 = bf16_rn(va.x - bf16_to_f(h0));
            const unsigned short l1 = bf16_rn(va.y - bf16_to_f(h1));
            const unsigned short l2 = bf16_rn(va.z - bf16_to_f(h2));
            const unsigned short l3 = bf16_rn(va.w - bf16_to_f(h3));
            const int addr = sw_addr(sr, (sc + q * 4) * 2);
            *(uint2*)((char*)AsH + addr) =
                make_uint2((unsigned)h0 | ((unsigned)h1 << 16),
                           (unsigned)h2 | ((unsigned)h3 << 16));
            *(uint2*)((char*)AsL + addr) =
                make_uint2((unsigned)l0 | ((unsigned)l1 << 16),
                           (unsigned)l2 | ((unsigned)l3 << 16));
        }
        __syncthreads();   // compiler emits vmcnt(0)+lgkmcnt(0) drain

        // ---- fragment loads (swizzled) + 48 MFMAs ----
        bf16x8 ah[4], al[4], bh[4], bl[4];
        const int kb = (lane >> 4) * 16;     // this lane's 8-elem k-chunk (bytes)
        #pragma unroll
        for (int f = 0; f < 4; ++f) {
            const int aaddr = sw_addr(f * 16 + (lane & 15), kb);
            ah[f] = *(const bf16x8*)((const char*)AsH + aaddr);
            al[f] = *(const bf16x8*)((const char*)AsL + aaddr);
            const int baddr = sw_addr(wn + f * 16 + (lane & 15), kb);
            bh[f] = *(const bf16x8*)((const char*)BsH + baddr);
            bl[f] = *(const bf16x8*)((const char*)BsL + baddr);
        }
        #pragma unroll
        for (int mi = 0; mi < 4; ++mi)
            #pragma unroll
            for (int ni = 0; ni < 4; ++ni) {
                acc[mi][ni] = __builtin_amdgcn_mfma_f32_16x16x32_bf16(
                    ah[mi], bh[ni], acc[mi][ni], 0, 0, 0);
                acc[mi][ni] = __builtin_amdgcn_mfma_f32_16x16x32_bf16(
                    ah[mi], bl[ni], acc[mi][ni], 0, 0, 0);
                acc[mi][ni] = __builtin_amdgcn_mfma_f32_16x16x32_bf16(
                    al[mi], bh[ni], acc[mi][ni], 0, 0, 0);
            }
        __syncthreads();
    }

    // ---- epilogue: C/D layout col=lane&15, row=(lane>>4)*4+reg (m89) ----
    #pragma unroll
    for (int mi = 0; mi < 4; ++mi) {
        #pragma unroll
        for (int j = 0; j < 4; ++j) {
            const int m = m0 + mi * 16 + ((lane >> 4) << 2) + j;
            if (m >= M) continue;
            #pragma unroll
            for (int ni = 0; ni < 4; ++ni) {
                const int n = wn + ni * 16 + (lane & 15);
                C[(size_t)m * 256 + n] = acc[mi][ni][j] + bias[n];
            }
        }
    }
}

// ---------------------------------------------------------------------------
// Generic tiled GEMM: C[M,N] = A[M,K] @ B[N,K]^T + bias[N]
// 64x64 tile, 256 threads, 4x4 micro-tile.  (validated round 3/5)
// ---------------------------------------------------------------------------
template<int TM, int TN, int TK>
__global__ __launch_bounds__(256) void gemm_abt_bias(
    const float* __restrict__ A, const float* __restrict__ B,
    const float* __restrict__ bias, float* __restrict__ C,
    int M, int N, int K)
{
    __shared__ float As[TK][TM + 4];
    __shared__ float Bs[TK][TN + 4];
    const int tid = threadIdx.x;
    const int m0 = blockIdx.y * TM;
    const int n0 = blockIdx.x * TN;
    const int tx = tid & 15;
    const int ty = tid >> 4;
    const int ar  = tid >> 2;
    const int ac4 = (tid & 3) << 2;

    float acc[4][4] = {};

    for (int k0 = 0; k0 < K; k0 += TK) {
        {
            const int m = m0 + ar;
            float4 va = make_float4(0.f, 0.f, 0.f, 0.f);
            if (m < M) va = *(const float4*)(A + (size_t)m * K + k0 + ac4);
            As[ac4 + 0][ar] = va.x; As[ac4 + 1][ar] = va.y;
            As[ac4 + 2][ar] = va.z; As[ac4 + 3][ar] = va.w;

            const int n = n0 + ar;
            const float4 vb = *(const float4*)(B + (size_t)n * K + k0 + ac4);
            Bs[ac4 + 0][ar] = vb.x; Bs[ac4 + 1][ar] = vb.y;
            Bs[ac4 + 2][ar] = vb.z; Bs[ac4 + 3][ar] = vb.w;
        }
        __syncthreads();

        #pragma unroll
        for (int k = 0; k < TK; ++k) {
            const float4 a4 = *(const float4*)(&As[k][ty << 2]);
            const float4 b4 = *(const float4*)(&Bs[k][tx << 2]);
            const float a[4] = {a4.x, a4.y, a4.z, a4.w};
            const float b[4] = {b4.x, b4.y, b4.z, b4.w};
            #pragma unroll
            for (int i = 0; i < 4; ++i)
                #pragma unroll
                for (int j = 0; j < 4; ++j)
                    acc[i][j] = fmaf(a[i], b[j], acc[i][j]);
        }
        __syncthreads();
    }

    #pragma unroll
    for (int i = 0; i < 4; ++i) {
        const int m = m0 + (ty << 2) + i;
        if (m >= M) continue;
        #pragma unroll
        for (int j = 0; j < 4; ++j) {
            const int n = n0 + (tx << 2) + j;
            C[(size_t)m * N + n] = acc[i][j] + bias[n];
        }
    }
}

// ---------------------------------------------------------------------------
// Fused query GEMM: C[M,384] = query @ [w_off; w_attn]^T + [b_off; b_attn].
// (validated round 5)
// ---------------------------------------------------------------------------
__global__ __launch_bounds__(256) void gemm_query_fused(
    const float* __restrict__ A,
    const float* __restrict__ Boff,  const float* __restrict__ Battn,
    const float* __restrict__ boff,  const float* __restrict__ battn,
    float* __restrict__ C, int M, int K)
{
    constexpr int TM = 64, TN = 64, TK = 16;
    __shared__ float As[TK][TM + 4];
    __shared__ float Bs[TK][TN + 4];
    const int tid = threadIdx.x;
    const int m0 = blockIdx.y * TM;
    const int n0 = blockIdx.x * TN;
    const bool isAttn = (n0 >= 256);
    const float* __restrict__ B  = isAttn ? Battn : Boff;
    const float* __restrict__ bv = isAttn ? battn : boff;
    const int nbase = isAttn ? (n0 - 256) : n0;

    const int tx = tid & 15;
    const int ty = tid >> 4;
    const int ar  = tid >> 2;
    const int ac4 = (tid & 3) << 2;

    float acc[4][4] = {};

    for (int k0 = 0; k0 < K; k0 += TK) {
        {
            const int m = m0 + ar;
            float4 va = make_float4(0.f, 0.f, 0.f, 0.f);
            if (m < M) va = *(const float4*)(A + (size_t)m * K + k0 + ac4);
            As[ac4 + 0][ar] = va.x; As[ac4 + 1][ar] = va.y;
            As[ac4 + 2][ar] = va.z; As[ac4 + 3][ar] = va.w;

            const float4 vb = *(const float4*)(B + (size_t)(nbase + ar) * K + k0 + ac4);
            Bs[ac4 + 0][ar] = vb.x; Bs[ac4 + 1][ar] = vb.y;
            Bs[ac4 + 2][ar] = vb.z; Bs[ac4 + 3][ar] = vb.w;
        }
        __syncthreads();

        #pragma unroll
        for (int k = 0; k < TK; ++k) {
            const float4 a4 = *(const float4*)(&As[k][ty << 2]);
            const float4 b4 = *(const float4*)(&Bs[k][tx << 2]);
            const float a[4] = {a4.x, a4.y, a4.z, a4.w};
            const float b[4] = {b4.x, b4.y, b4.z, b4.w};
            #pragma unroll
            for (int i = 0; i < 4; ++i)
                #pragma unroll
                for (int j = 0; j < 4; ++j)
                    acc[i][j] = fmaf(a[i], b[j], acc[i][j]);
        }
        __syncthreads();
    }

    #pragma unroll
    for (int i = 0; i < 4; ++i) {
        const int m = m0 + (ty << 2) + i;
        if (m >= M) continue;
        #pragma unroll
        for (int j = 0; j < 4; ++j) {
            const int nl = (tx << 2) + j;
            C[(size_t)m * NQOUT + n0 + nl] = acc[i][j] + bv[nbase + nl];
        }
    }
}

// ---------------------------------------------------------------------------
// Deformable sampling with fused 16-way softmax. (validated round 5)
// ---------------------------------------------------------------------------
__global__ __launch_bounds__(256) void ms_sample_kernel(
    const float* __restrict__ vproj,   // [bs, Lv, 256]
    const float* __restrict__ refp,    // [bs, Lq, 4, 2]
    const float* __restrict__ qout,    // [bs, Lq, 384]
    const int*   __restrict__ shapes,  // [4][2] = (H, W)
    const int*   __restrict__ startix, // [4]
    float* __restrict__ sampled,       // [bs, Lq, 256]
    int Lq, int Lv)
{
    __shared__ float aw_lds[HEADS * LEVELS * POINTS];

    const int bq = blockIdx.x;
    const int b  = bq / Lq;
    const int tid = threadIdx.x;
    const int h = tid >> 5, d = tid & 31;

    const float* vb   = vproj + (size_t)b * Lv * EMBED;
    const float* rowq = qout + (size_t)bq * NQOUT;
    const float* offq = rowq;
    const float* logq = rowq + 256;
    const float* refq = refp + (size_t)bq * LEVELS * 2;

    if (tid < HEADS * LEVELS * POINTS) {
        const float v = logq[tid];
        float m = v;
        #pragma unroll
        for (int s = 8; s > 0; s >>= 1) m = fmaxf(m, __shfl_xor(m, s, 16));
        const float e = __expf(v - m);
        float sum = e;
        #pragma unroll
        for (int s = 8; s > 0; s >>= 1) sum += __shfl_xor(sum, s, 16);
        aw_lds[tid] = e / sum;
    }
    __syncthreads();

    float accv = 0.f;
    #pragma unroll
    for (int l = 0; l < LEVELS; ++l) {
        const int H = shapes[l * 2 + 0];
        const int W = shapes[l * 2 + 1];
        const int st = startix[l];
        const float fW = (float)W, fH = (float)H;
        const float rx = refq[l * 2 + 0];
        const float ry = refq[l * 2 + 1];
        #pragma unroll
        for (int p = 0; p < POINTS; ++p) {
            const int oi = (((h * LEVELS + l) * POINTS) + p) * 2;
            const float ox = offq[oi + 0];
            const float oy = offq[oi + 1];
            const float aw = aw_lds[(h * LEVELS + l) * POINTS + p];
            const float x = (rx + ox / fW) * fW - 0.5f;
            const float y = (ry + oy / fH) * fH - 0.5f;
            const float x0f = floorf(x), y0f = floorf(y);
            const float lx = x - x0f, ly = y - y0f;
            const int x0 = (int)x0f, y0 = (int)y0f;
            float s = 0.f;
            #pragma unroll
            for (int c = 0; c < 4; ++c) {
                const int xi = x0 + (c & 1);
                const int yi = y0 + (c >> 1);
                const float wx = (c & 1) ? lx : 1.f - lx;
                const float wy = (c >> 1) ? ly : 1.f - ly;
                const bool valid = (xi >= 0) && (xi < W) && (yi >= 0) && (yi < H);
                const int xc = min(max(xi, 0), W - 1);
                const int yc = min(max(yi, 0), H - 1);
                const float val = vb[(size_t)(st + yc * W + xc) * EMBED + (h << 5) + d];
                s = fmaf(valid ? wx * wy : 0.f, val, s);
            }
            accv = fmaf(aw, s, accv);
        }
    }
    sampled[(size_t)bq * EMBED + tid] = accv;
}

// ---------------------------------------------------------------------------
extern "C" void kernel_launch(void* const* d_in, const int* in_sizes, int n_in,
                              void* d_out, int out_size, void* d_ws, size_t ws_size,
                              hipStream_t stream)
{
    const float* query   = (const float*)d_in[0];
    const float* refp    = (const float*)d_in[1];
    const float* value   = (const float*)d_in[2];
    const int*   shapes  = (const int*)d_in[3];
    const int*   startix = (const int*)d_in[4];
    const float* w_value = (const float*)d_in[5];
    const float* b_value = (const float*)d_in[6];
    const float* w_off   = (const float*)d_in[7];
    const float* b_off   = (const float*)d_in[8];
    const float* w_attn  = (const float*)d_in[9];
    const float* b_attn  = (const float*)d_in[10];
    const float* w_out   = (const float*)d_in[11];
    const float* b_out   = (const float*)d_in[12];
    float* out = (float*)d_out;

    const int bs = 4;
    const int Lq = in_sizes[0] / (bs * EMBED);   // 900
    const int Lv = in_sizes[2] / (bs * EMBED);   // 13294
    const int BQ = bs * Lq;                      // 3600
    const int M  = bs * Lv;                      // 53176

    float* ws = (float*)d_ws;
    float* vproj   = ws; ws += (size_t)bs * Lv * EMBED;   // 54.5 MB
    float* qoutb   = ws; ws += (size_t)BQ * NQOUT;        // 5.5 MB
    float* sampled = ws; ws += (size_t)BQ * EMBED;        // 3.7 MB
    unsigned short* bhi = (unsigned short*)ws;            // 128 KB
    unsigned short* blo = bhi + 256 * 256;                // 128 KB

    // 0. prep: weight -> swizzled hi/lo bf16 LDS images
    hipLaunchKernelGGL(prep_w, dim3(8), dim3(256), 0, stream, w_value, bhi, blo);

    // 1. value projection via bf16-split MFMA (64x256 tile, gload_lds B)
    hipLaunchKernelGGL(vproj_mfma, dim3((M + 63) / 64), dim3(256), 0, stream,
                       value, bhi, blo, b_value, vproj, M);

    // 2. fused query GEMM: offsets (N=256) + attn logits (N=128)
    {
        dim3 grid(NQOUT / 64, (BQ + 63) / 64);
        hipLaunchKernelGGL(gemm_query_fused, grid, dim3(256), 0, stream,
                           query, w_off, w_attn, b_off, b_attn, qoutb, BQ, EMBED);
    }
    // 3. deformable sampling with fused softmax
    hipLaunchKernelGGL(ms_sample_kernel, dim3(BQ), dim3(256), 0, stream,
                       vproj, refp, qoutb, shapes, startix, sampled, Lq, Lv);

    // 4. output projection: [BQ,256] @ w_out.T -> d_out
    {
        dim3 grid(EMBED / 64, (BQ + 63) / 64);
        hipLaunchKernelGGL((gemm_abt_bias<64, 64, 16>), grid, dim3(256), 0, stream,
                           sampled, w_out, b_out, out, BQ, EMBED, EMBED);
    }
}

// Round 9
// 218.063 us; speedup vs baseline: 1.2540x; 1.0165x over previous
//
#include <hip/hip_runtime.h>
#include <cstddef>

#define EMBED 256
#define HEADS 8
#define LEVELS 4
#define POINTS 4
#define NQOUT 384   // 256 offset outputs + 128 attn logits per query row

typedef __attribute__((ext_vector_type(8))) short bf16x8;
typedef __attribute__((ext_vector_type(4))) float f32x4;

__device__ __forceinline__ unsigned short bf16_rn(float x) {
    union { float f; unsigned u; } v; v.f = x;
    const unsigned r = v.u + 0x7fffu + ((v.u >> 16) & 1u);
    return (unsigned short)(r >> 16);
}
__device__ __forceinline__ float bf16_to_f(unsigned short h) {
    union { unsigned u; float f; } v; v.u = (unsigned)h << 16;
    return v.f;
}
// swizzled byte offset within a [rows][32]-bf16 tile of 64B rows (T2/G4 fix)
__device__ __forceinline__ int sw_addr(int row, int byte_in_row) {
    return (row * 64 + byte_in_row) ^ ((row & 7) << 4);
}

// ---------------------------------------------------------------------------
// Prep: convert w_value [256x256] fp32 -> hi/lo bf16 images laid out exactly
// as the GEMM's swizzled LDS B-tiles: img[kp][sw_addr(r, kk*2)], kp = k/32.
// (validated round 8)
// ---------------------------------------------------------------------------
__global__ __launch_bounds__(256) void prep_w(
    const float* __restrict__ w,
    unsigned short* __restrict__ hi, unsigned short* __restrict__ lo)
{
    const int t  = blockIdx.x * 256 + threadIdx.x;   // 0..2047
    const int r  = t >> 3;
    const int kp = t & 7;
    const float* src = w + (size_t)r * 256 + kp * 32;
    #pragma unroll
    for (int c = 0; c < 4; ++c) {                    // 4 chunks of 8 elems (16B)
        unsigned hw[4], lw[4];
        #pragma unroll
        for (int j = 0; j < 4; ++j) {
            const float f0 = src[c * 8 + j * 2 + 0];
            const float f1 = src[c * 8 + j * 2 + 1];
            const unsigned short h0 = bf16_rn(f0), h1 = bf16_rn(f1);
            const unsigned short l0 = bf16_rn(f0 - bf16_to_f(h0));
            const unsigned short l1 = bf16_rn(f1 - bf16_to_f(h1));
            hw[j] = (unsigned)h0 | ((unsigned)h1 << 16);
            lw[j] = (unsigned)l0 | ((unsigned)l1 << 16);
        }
        const int addr = kp * 16384 + sw_addr(r, c * 16);
        *(uint4*)((char*)hi + addr) = make_uint4(hw[0], hw[1], hw[2], hw[3]);
        *(uint4*)((char*)lo + addr) = make_uint4(lw[0], lw[1], lw[2], lw[3]);
    }
}

// ---------------------------------------------------------------------------
// Value projection via bf16-split MFMA, v3: 2-phase double-buffered k-loop.
// C[M,256] = A[M,256] @ B[256,256]^T + bias;  C ~= Ah*Bh + Ah*Bl + Al*Bh.
// Tile 64(M) x 256(N), BK=32, 4 waves side by side. Panel kp+1's
// global_load_lds + A-convert issue at the TOP of iteration kp, so the
// end-of-iteration barrier's vmcnt(0) drain is covered by the ds_read+MFMA
// of panel kp (round-8 PMC: MfmaUtil=VALUBusy=Occ=14% -> latency-bound on
// the per-panel drain). LDS 80KB (A 2x8KB, B 2x64KB... 2x(4+4)+2x(16+16))
// -> 2 blocks/CU.
// ---------------------------------------------------------------------------
__global__ __launch_bounds__(256) void vproj_mfma(
    const float* __restrict__ A,
    const unsigned short* __restrict__ Bhi, const unsigned short* __restrict__ Blo,
    const float* __restrict__ bias, float* __restrict__ C, int M)
{
    __shared__ unsigned short AsH[2][64 * 32], AsL[2][64 * 32];    // 2 x 4KB each
    __shared__ unsigned short BsH[2][256 * 32], BsL[2][256 * 32];  // 2 x 16KB each

    const int tid  = threadIdx.x;
    const int lane = tid & 63;
    const int wn   = (tid >> 6) * 64;        // wave col offset (0,64,128,192)
    const int m0   = blockIdx.x * 64;

    // A staging role: row sr, 8 floats starting at sc
    const int sr = tid >> 2;                 // 0..63
    const int sc = (tid & 3) * 8;            // 0,8,16,24
    const bool mok = (m0 + sr) < M;
    const float* ga = A + (size_t)(m0 + sr) * 256 + sc;

    // B staging: byte-identical image copy, lds dest = wave base + lane*16
    const int wbase = (tid & 192) * 16;      // wid*1024

    f32x4 acc[4][4] = {};

// STAGE(buf, kpi): issue 8 global_load_lds for B panel kpi into buf, and
// convert+ds_write the A panel kpi into buf. Kept as a macro so the
// address-space casts stay in the exact (HW-validated, round 8) form.
#define STAGE(buf, kpi)                                                       \
    do {                                                                      \
        _Pragma("unroll")                                                     \
        for (int i = 0; i < 4; ++i) {                                         \
            const int off = i * 4096 + wbase + (lane << 4);                   \
            __builtin_amdgcn_global_load_lds(                                 \
                (const __attribute__((address_space(1))) unsigned int*)       \
                    ((const char*)Bhi + (kpi) * 16384 + off),                 \
                (__attribute__((address_space(3))) unsigned int*)             \
                    ((char*)BsH + (buf) * 16384 + i * 4096 + wbase),          \
                16, 0, 0);                                                    \
            __builtin_amdgcn_global_load_lds(                                 \
                (const __attribute__((address_space(1))) unsigned int*)       \
                    ((const char*)Blo + (kpi) * 16384 + off),                 \
                (__attribute__((address_space(3))) unsigned int*)             \
                    ((char*)BsL + (buf) * 16384 + i * 4096 + wbase),          \
                16, 0, 0);                                                    \
        }                                                                     \
        _Pragma("unroll")                                                     \
        for (int q = 0; q < 2; ++q) {                                         \
            float4 va = make_float4(0.f, 0.f, 0.f, 0.f);                      \
            if (mok) va = *(const float4*)(ga + (kpi) * 32 + q * 4);          \
            const unsigned short h0 = bf16_rn(va.x), h1 = bf16_rn(va.y);      \
            const unsigned short h2 = bf16_rn(va.z), h3 = bf16_rn(va.w);      \
            const unsigned short l0 = bf16_rn(va.x - bf16_to_f(h0));          \
            const unsigned short l1 = bf16_rn(va.y - bf16_to_f(h1));          \
            const unsigned short l2 = bf16_rn(va.z - bf16_to_f(h2));          \
            const unsigned short l3 = bf16_rn(va.w - bf16_to_f(h3));          \
            const int addr = (buf) * 4096 + sw_addr(sr, (sc + q * 4) * 2);    \
            *(uint2*)((char*)AsH + addr) =                                    \
                make_uint2((unsigned)h0 | ((unsigned)h1 << 16),               \
                           (unsigned)h2 | ((unsigned)h3 << 16));              \
            *(uint2*)((char*)AsL + addr) =                                    \
                make_uint2((unsigned)l0 | ((unsigned)l1 << 16),               \
                           (unsigned)l2 | ((unsigned)l3 << 16));              \
        }                                                                     \
    } while (0)

    // prologue: fill buffer 0 with panel 0, drain
    STAGE(0, 0);
    __syncthreads();

    for (int kp = 0; kp < 8; ++kp) {
        const int cur = kp & 1;
        // issue next panel's loads FIRST — latency hides under this panel's
        // ds_read + MFMA; the barrier below drains them once per panel.
        if (kp < 7) STAGE(cur ^ 1, kp + 1);

        // ---- fragment loads (swizzled) + 48 MFMAs on buffer `cur` ----
        bf16x8 ah[4], al[4], bh[4], bl[4];
        const int kb = (lane >> 4) * 16;     // this lane's 8-elem k-chunk (bytes)
        #pragma unroll
        for (int f = 0; f < 4; ++f) {
            const int aaddr = cur * 4096 + sw_addr(f * 16 + (lane & 15), kb);
            ah[f] = *(const bf16x8*)((const char*)AsH + aaddr);
            al[f] = *(const bf16x8*)((const char*)AsL + aaddr);
            const int baddr = cur * 16384 + sw_addr(wn + f * 16 + (lane & 15), kb);
            bh[f] = *(const bf16x8*)((const char*)BsH + baddr);
            bl[f] = *(const bf16x8*)((const char*)BsL + baddr);
        }
        #pragma unroll
        for (int mi = 0; mi < 4; ++mi)
            #pragma unroll
            for (int ni = 0; ni < 4; ++ni) {
                acc[mi][ni] = __builtin_amdgcn_mfma_f32_16x16x32_bf16(
                    ah[mi], bh[ni], acc[mi][ni], 0, 0, 0);
                acc[mi][ni] = __builtin_amdgcn_mfma_f32_16x16x32_bf16(
                    ah[mi], bl[ni], acc[mi][ni], 0, 0, 0);
                acc[mi][ni] = __builtin_amdgcn_mfma_f32_16x16x32_bf16(
                    al[mi], bh[ni], acc[mi][ni], 0, 0, 0);
            }
        __syncthreads();   // waits for this iteration's STAGE into buf cur^1
    }
#undef STAGE

    // ---- epilogue: C/D layout col=lane&15, row=(lane>>4)*4+reg (m89) ----
    #pragma unroll
    for (int mi = 0; mi < 4; ++mi) {
        #pragma unroll
        for (int j = 0; j < 4; ++j) {
            const int m = m0 + mi * 16 + ((lane >> 4) << 2) + j;
            if (m >= M) continue;
            #pragma unroll
            for (int ni = 0; ni < 4; ++ni) {
                const int n = wn + ni * 16 + (lane & 15);
                C[(size_t)m * 256 + n] = acc[mi][ni][j] + bias[n];
            }
        }
    }
}

// ---------------------------------------------------------------------------
// Generic tiled GEMM: C[M,N] = A[M,K] @ B[N,K]^T + bias[N]
// 64x64 tile, 256 threads, 4x4 micro-tile.  (validated rounds 3/5/8)
// ---------------------------------------------------------------------------
template<int TM, int TN, int TK>
__global__ __launch_bounds__(256) void gemm_abt_bias(
    const float* __restrict__ A, const float* __restrict__ B,
    const float* __restrict__ bias, float* __restrict__ C,
    int M, int N, int K)
{
    __shared__ float As[TK][TM + 4];
    __shared__ float Bs[TK][TN + 4];
    const int tid = threadIdx.x;
    const int m0 = blockIdx.y * TM;
    const int n0 = blockIdx.x * TN;
    const int tx = tid & 15;
    const int ty = tid >> 4;
    const int ar  = tid >> 2;
    const int ac4 = (tid & 3) << 2;

    float acc[4][4] = {};

    for (int k0 = 0; k0 < K; k0 += TK) {
        {
            const int m = m0 + ar;
            float4 va = make_float4(0.f, 0.f, 0.f, 0.f);
            if (m < M) va = *(const float4*)(A + (size_t)m * K + k0 + ac4);
            As[ac4 + 0][ar] = va.x; As[ac4 + 1][ar] = va.y;
            As[ac4 + 2][ar] = va.z; As[ac4 + 3][ar] = va.w;

            const int n = n0 + ar;
            const float4 vb = *(const float4*)(B + (size_t)n * K + k0 + ac4);
            Bs[ac4 + 0][ar] = vb.x; Bs[ac4 + 1][ar] = vb.y;
            Bs[ac4 + 2][ar] = vb.z; Bs[ac4 + 3][ar] = vb.w;
        }
        __syncthreads();

        #pragma unroll
        for (int k = 0; k < TK; ++k) {
            const float4 a4 = *(const float4*)(&As[k][ty << 2]);
            const float4 b4 = *(const float4*)(&Bs[k][tx << 2]);
            const float a[4] = {a4.x, a4.y, a4.z, a4.w};
            const float b[4] = {b4.x, b4.y, b4.z, b4.w};
            #pragma unroll
            for (int i = 0; i < 4; ++i)
                #pragma unroll
                for (int j = 0; j < 4; ++j)
                    acc[i][j] = fmaf(a[i], b[j], acc[i][j]);
        }
        __syncthreads();
    }

    #pragma unroll
    for (int i = 0; i < 4; ++i) {
        const int m = m0 + (ty << 2) + i;
        if (m >= M) continue;
        #pragma unroll
        for (int j = 0; j < 4; ++j) {
            const int n = n0 + (tx << 2) + j;
            C[(size_t)m * N + n] = acc[i][j] + bias[n];
        }
    }
}

// ---------------------------------------------------------------------------
// Fused query GEMM: C[M,384] = query @ [w_off; w_attn]^T + [b_off; b_attn].
// (validated rounds 5/8)
// ---------------------------------------------------------------------------
__global__ __launch_bounds__(256) void gemm_query_fused(
    const float* __restrict__ A,
    const float* __restrict__ Boff,  const float* __restrict__ Battn,
    const float* __restrict__ boff,  const float* __restrict__ battn,
    float* __restrict__ C, int M, int K)
{
    constexpr int TM = 64, TN = 64, TK = 16;
    __shared__ float As[TK][TM + 4];
    __shared__ float Bs[TK][TN + 4];
    const int tid = threadIdx.x;
    const int m0 = blockIdx.y * TM;
    const int n0 = blockIdx.x * TN;
    const bool isAttn = (n0 >= 256);
    const float* __restrict__ B  = isAttn ? Battn : Boff;
    const float* __restrict__ bv = isAttn ? battn : boff;
    const int nbase = isAttn ? (n0 - 256) : n0;

    const int tx = tid & 15;
    const int ty = tid >> 4;
    const int ar  = tid >> 2;
    const int ac4 = (tid & 3) << 2;

    float acc[4][4] = {};

    for (int k0 = 0; k0 < K; k0 += TK) {
        {
            const int m = m0 + ar;
            float4 va = make_float4(0.f, 0.f, 0.f, 0.f);
            if (m < M) va = *(const float4*)(A + (size_t)m * K + k0 + ac4);
            As[ac4 + 0][ar] = va.x; As[ac4 + 1][ar] = va.y;
            As[ac4 + 2][ar] = va.z; As[ac4 + 3][ar] = va.w;

            const float4 vb = *(const float4*)(B + (size_t)(nbase + ar) * K + k0 + ac4);
            Bs[ac4 + 0][ar] = vb.x; Bs[ac4 + 1][ar] = vb.y;
            Bs[ac4 + 2][ar] = vb.z; Bs[ac4 + 3][ar] = vb.w;
        }
        __syncthreads();

        #pragma unroll
        for (int k = 0; k < TK; ++k) {
            const float4 a4 = *(const float4*)(&As[k][ty << 2]);
            const float4 b4 = *(const float4*)(&Bs[k][tx << 2]);
            const float a[4] = {a4.x, a4.y, a4.z, a4.w};
            const float b[4] = {b4.x, b4.y, b4.z, b4.w};
            #pragma unroll
            for (int i = 0; i < 4; ++i)
                #pragma unroll
                for (int j = 0; j < 4; ++j)
                    acc[i][j] = fmaf(a[i], b[j], acc[i][j]);
        }
        __syncthreads();
    }

    #pragma unroll
    for (int i = 0; i < 4; ++i) {
        const int m = m0 + (ty << 2) + i;
        if (m >= M) continue;
        #pragma unroll
        for (int j = 0; j < 4; ++j) {
            const int nl = (tx << 2) + j;
            C[(size_t)m * NQOUT + n0 + nl] = acc[i][j] + bv[nbase + nl];
        }
    }
}

// ---------------------------------------------------------------------------
// Deformable sampling with fused 16-way softmax. (validated rounds 5/8)
// ---------------------------------------------------------------------------
__global__ __launch_bounds__(256) void ms_sample_kernel(
    const float* __restrict__ vproj,   // [bs, Lv, 256]
    const float* __restrict__ refp,    // [bs, Lq, 4, 2]
    const float* __restrict__ qout,    // [bs, Lq, 384]
    const int*   __restrict__ shapes,  // [4][2] = (H, W)
    const int*   __restrict__ startix, // [4]
    float* __restrict__ sampled,       // [bs, Lq, 256]
    int Lq, int Lv)
{
    __shared__ float aw_lds[HEADS * LEVELS * POINTS];

    const int bq = blockIdx.x;
    const int b  = bq / Lq;
    const int tid = threadIdx.x;
    const int h = tid >> 5, d = tid & 31;

    const float* vb   = vproj + (size_t)b * Lv * EMBED;
    const float* rowq = qout + (size_t)bq * NQOUT;
    const float* offq = rowq;
    const float* logq = rowq + 256;
    const float* refq = refp + (size_t)bq * LEVELS * 2;

    if (tid < HEADS * LEVELS * POINTS) {
        const float v = logq[tid];
        float m = v;
        #pragma unroll
        for (int s = 8; s > 0; s >>= 1) m = fmaxf(m, __shfl_xor(m, s, 16));
        const float e = __expf(v - m);
        float sum = e;
        #pragma unroll
        for (int s = 8; s > 0; s >>= 1) sum += __shfl_xor(sum, s, 16);
        aw_lds[tid] = e / sum;
    }
    __syncthreads();

    float accv = 0.f;
    #pragma unroll
    for (int l = 0; l < LEVELS; ++l) {
        const int H = shapes[l * 2 + 0];
        const int W = shapes[l * 2 + 1];
        const int st = startix[l];
        const float fW = (float)W, fH = (float)H;
        const float rx = refq[l * 2 + 0];
        const float ry = refq[l * 2 + 1];
        #pragma unroll
        for (int p = 0; p < POINTS; ++p) {
            const int oi = (((h * LEVELS + l) * POINTS) + p) * 2;
            const float ox = offq[oi + 0];
            const float oy = offq[oi + 1];
            const float aw = aw_lds[(h * LEVELS + l) * POINTS + p];
            const float x = (rx + ox / fW) * fW - 0.5f;
            const float y = (ry + oy / fH) * fH - 0.5f;
            const float x0f = floorf(x), y0f = floorf(y);
            const float lx = x - x0f, ly = y - y0f;
            const int x0 = (int)x0f, y0 = (int)y0f;
            float s = 0.f;
            #pragma unroll
            for (int c = 0; c < 4; ++c) {
                const int xi = x0 + (c & 1);
                const int yi = y0 + (c >> 1);
                const float wx = (c & 1) ? lx : 1.f - lx;
                const float wy = (c >> 1) ? ly : 1.f - ly;
                const bool valid = (xi >= 0) && (xi < W) && (yi >= 0) && (yi < H);
                const int xc = min(max(xi, 0), W - 1);
                const int yc = min(max(yi, 0), H - 1);
                const float val = vb[(size_t)(st + yc * W + xc) * EMBED + (h << 5) + d];
                s = fmaf(valid ? wx * wy : 0.f, val, s);
            }
            accv = fmaf(aw, s, accv);
        }
    }
    sampled[(size_t)bq * EMBED + tid] = accv;
}

// ---------------------------------------------------------------------------
extern "C" void kernel_launch(void* const* d_in, const int* in_sizes, int n_in,
                              void* d_out, int out_size, void* d_ws, size_t ws_size,
                              hipStream_t stream)
{
    const float* query   = (const float*)d_in[0];
    const float* refp    = (const float*)d_in[1];
    const float* value   = (const float*)d_in[2];
    const int*   shapes  = (const int*)d_in[3];
    const int*   startix = (const int*)d_in[4];
    const float* w_value = (const float*)d_in[5];
    const float* b_value = (const float*)d_in[6];
    const float* w_off   = (const float*)d_in[7];
    const float* b_off   = (const float*)d_in[8];
    const float* w_attn  = (const float*)d_in[9];
    const float* b_attn  = (const float*)d_in[10];
    const float* w_out   = (const float*)d_in[11];
    const float* b_out   = (const float*)d_in[12];
    float* out = (float*)d_out;

    const int bs = 4;
    const int Lq = in_sizes[0] / (bs * EMBED);   // 900
    const int Lv = in_sizes[2] / (bs * EMBED);   // 13294
    const int BQ = bs * Lq;                      // 3600
    const int M  = bs * Lv;                      // 53176

    float* ws = (float*)d_ws;
    float* vproj   = ws; ws += (size_t)bs * Lv * EMBED;   // 54.5 MB
    float* qoutb   = ws; ws += (size_t)BQ * NQOUT;        // 5.5 MB
    float* sampled = ws; ws += (size_t)BQ * EMBED;        // 3.7 MB
    unsigned short* bhi = (unsigned short*)ws;            // 128 KB
    unsigned short* blo = bhi + 256 * 256;                // 128 KB

    // 0. prep: weight -> swizzled hi/lo bf16 LDS images
    hipLaunchKernelGGL(prep_w, dim3(8), dim3(256), 0, stream, w_value, bhi, blo);

    // 1. value projection via bf16-split MFMA (2-phase double-buffered)
    hipLaunchKernelGGL(vproj_mfma, dim3((M + 63) / 64), dim3(256), 0, stream,
                       value, bhi, blo, b_value, vproj, M);

    // 2. fused query GEMM: offsets (N=256) + attn logits (N=128)
    {
        dim3 grid(NQOUT / 64, (BQ + 63) / 64);
        hipLaunchKernelGGL(gemm_query_fused, grid, dim3(256), 0, stream,
                           query, w_off, w_attn, b_off, b_attn, qoutb, BQ, EMBED);
    }
    // 3. deformable sampling with fused softmax
    hipLaunchKernelGGL(ms_sample_kernel, dim3(BQ), dim3(256), 0, stream,
                       vproj, refp, qoutb, shapes, startix, sampled, Lq, Lv);

    // 4. output projection: [BQ,256] @ w_out.T -> d_out
    {
        dim3 grid(EMBED / 64, (BQ + 63) / 64);
        hipLaunchKernelGGL((gemm_abt_bias<64, 64, 16>), grid, dim3(256), 0, stream,
                           sampled, w_out, b_out, out, BQ, EMBED, EMBED);
    }
}

// Round 10
// 211.201 us; speedup vs baseline: 1.2947x; 1.0325x over previous
//
#include <hip/hip_runtime.h>
#include <cstddef>

#define EMBED 256
#define HEADS 8
#define LEVELS 4
#define POINTS 4
#define NQOUT 384   // 256 offset outputs + 128 attn logits per query row

typedef __attribute__((ext_vector_type(8))) short bf16x8;
typedef __attribute__((ext_vector_type(4))) float f32x4;

__device__ __forceinline__ unsigned short bf16_rn(float x) {
    union { float f; unsigned u; } v; v.f = x;
    const unsigned r = v.u + 0x7fffu + ((v.u >> 16) & 1u);
    return (unsigned short)(r >> 16);
}
__device__ __forceinline__ float bf16_to_f(unsigned short h) {
    union { unsigned u; float f; } v; v.u = (unsigned)h << 16;
    return v.f;
}
// swizzled byte offset within a [rows][32]-bf16 tile of 64B rows (T2/G4 fix)
__device__ __forceinline__ int sw_addr(int row, int byte_in_row) {
    return (row * 64 + byte_in_row) ^ ((row & 7) << 4);
}

// ---------------------------------------------------------------------------
// Prep: convert w_value [256x256] fp32 -> hi/lo bf16 images laid out exactly
// as the GEMM's swizzled LDS B-tiles. (validated rounds 8/9)
// ---------------------------------------------------------------------------
__global__ __launch_bounds__(256) void prep_w(
    const float* __restrict__ w,
    unsigned short* __restrict__ hi, unsigned short* __restrict__ lo)
{
    const int t  = blockIdx.x * 256 + threadIdx.x;   // 0..2047
    const int r  = t >> 3;
    const int kp = t & 7;
    const float* src = w + (size_t)r * 256 + kp * 32;
    #pragma unroll
    for (int c = 0; c < 4; ++c) {                    // 4 chunks of 8 elems (16B)
        unsigned hw[4], lw[4];
        #pragma unroll
        for (int j = 0; j < 4; ++j) {
            const float f0 = src[c * 8 + j * 2 + 0];
            const float f1 = src[c * 8 + j * 2 + 1];
            const unsigned short h0 = bf16_rn(f0), h1 = bf16_rn(f1);
            const unsigned short l0 = bf16_rn(f0 - bf16_to_f(h0));
            const unsigned short l1 = bf16_rn(f1 - bf16_to_f(h1));
            hw[j] = (unsigned)h0 | ((unsigned)h1 << 16);
            lw[j] = (unsigned)l0 | ((unsigned)l1 << 16);
        }
        const int addr = kp * 16384 + sw_addr(r, c * 16);
        *(uint4*)((char*)hi + addr) = make_uint4(hw[0], hw[1], hw[2], hw[3]);
        *(uint4*)((char*)lo + addr) = make_uint4(lw[0], lw[1], lw[2], lw[3]);
    }
}

// ---------------------------------------------------------------------------
// Value projection via bf16-split MFMA, v4: T14 async-STAGE split.
// Round-9 postmortem: the A float4 load was consumed by its convert
// IMMEDIATELY (same STAGE), so every panel ate full HBM latency before
// compute — double-buffering alone was null (52us, MfmaUtil 15%).
// v4 splits staging: [issue A->regs + B->lds for kp+1] BEFORE the
// ds_read+MFMA of kp; [convert regs -> ds_write buf^1] AFTER the MFMAs.
// The ~430cy compute phase now covers the load latency. 1 barrier/panel.
// ---------------------------------------------------------------------------
__global__ __launch_bounds__(256) void vproj_mfma(
    const float* __restrict__ A,
    const unsigned short* __restrict__ Bhi, const unsigned short* __restrict__ Blo,
    const float* __restrict__ bias, float* __restrict__ C, int M)
{
    __shared__ unsigned short AsH[2][64 * 32], AsL[2][64 * 32];    // 2 x 4KB each
    __shared__ unsigned short BsH[2][256 * 32], BsL[2][256 * 32];  // 2 x 16KB each

    const int tid  = threadIdx.x;
    const int lane = tid & 63;
    const int wn   = (tid >> 6) * 64;        // wave col offset (0,64,128,192)
    const int m0   = blockIdx.x * 64;

    // A staging role: row sr, 8 floats starting at sc
    const int sr = tid >> 2;                 // 0..63
    const int sc = (tid & 3) * 8;            // 0,8,16,24
    const bool mok = (m0 + sr) < M;
    const float* ga = A + (size_t)(m0 + sr) * 256 + sc;

    // B staging: byte-identical image copy, lds dest = wave base + lane*16
    const int wbase = (tid & 192) * 16;      // wid*1024

    f32x4 acc[4][4] = {};
    float4 va0, va1;                         // A prefetch registers (named: rule #20)

// issue A panel kpi's 2 float4 loads into va0/va1 (consumed LATER by WRITEA)
#define LOADA(kpi)                                                            \
    do {                                                                      \
        va0 = make_float4(0.f, 0.f, 0.f, 0.f);                                \
        va1 = make_float4(0.f, 0.f, 0.f, 0.f);                                \
        if (mok) {                                                            \
            va0 = *(const float4*)(ga + (kpi) * 32);                          \
            va1 = *(const float4*)(ga + (kpi) * 32 + 4);                      \
        }                                                                     \
    } while (0)

// issue 8 global_load_lds for B panel kpi into buffer `buf` (HW-validated form)
#define LOADB(buf, kpi)                                                       \
    do {                                                                      \
        _Pragma("unroll")                                                     \
        for (int i = 0; i < 4; ++i) {                                         \
            const int off = i * 4096 + wbase + (lane << 4);                   \
            __builtin_amdgcn_global_load_lds(                                 \
                (const __attribute__((address_space(1))) unsigned int*)       \
                    ((const char*)Bhi + (kpi) * 16384 + off),                 \
                (__attribute__((address_space(3))) unsigned int*)             \
                    ((char*)BsH + (buf) * 16384 + i * 4096 + wbase),          \
                16, 0, 0);                                                    \
            __builtin_amdgcn_global_load_lds(                                 \
                (const __attribute__((address_space(1))) unsigned int*)       \
                    ((const char*)Blo + (kpi) * 16384 + off),                 \
                (__attribute__((address_space(3))) unsigned int*)             \
                    ((char*)BsL + (buf) * 16384 + i * 4096 + wbase),          \
                16, 0, 0);                                                    \
        }                                                                     \
    } while (0)

// convert va0/va1 -> bf16 hi/lo, swizzled ds_write into buffer `buf`
#define WRITEA(buf)                                                           \
    do {                                                                      \
        const unsigned short h0 = bf16_rn(va0.x), h1 = bf16_rn(va0.y);        \
        const unsigned short h2 = bf16_rn(va0.z), h3 = bf16_rn(va0.w);        \
        const unsigned short l0 = bf16_rn(va0.x - bf16_to_f(h0));             \
        const unsigned short l1 = bf16_rn(va0.y - bf16_to_f(h1));             \
        const unsigned short l2 = bf16_rn(va0.z - bf16_to_f(h2));             \
        const unsigned short l3 = bf16_rn(va0.w - bf16_to_f(h3));             \
        const int a0 = (buf) * 4096 + sw_addr(sr, sc * 2);                    \
        *(uint2*)((char*)AsH + a0) =                                          \
            make_uint2((unsigned)h0 | ((unsigned)h1 << 16),                   \
                       (unsigned)h2 | ((unsigned)h3 << 16));                  \
        *(uint2*)((char*)AsL + a0) =                                          \
            make_uint2((unsigned)l0 | ((unsigned)l1 << 16),                   \
                       (unsigned)l2 | ((unsigned)l3 << 16));                  \
        const unsigned short h4 = bf16_rn(va1.x), h5 = bf16_rn(va1.y);        \
        const unsigned short h6 = bf16_rn(va1.z), h7 = bf16_rn(va1.w);        \
        const unsigned short l4 = bf16_rn(va1.x - bf16_to_f(h4));             \
        const unsigned short l5 = bf16_rn(va1.y - bf16_to_f(h5));             \
        const unsigned short l6 = bf16_rn(va1.z - bf16_to_f(h6));             \
        const unsigned short l7 = bf16_rn(va1.w - bf16_to_f(h7));             \
        const int a1 = (buf) * 4096 + sw_addr(sr, (sc + 4) * 2);              \
        *(uint2*)((char*)AsH + a1) =                                          \
            make_uint2((unsigned)h4 | ((unsigned)h5 << 16),                   \
                       (unsigned)h6 | ((unsigned)h7 << 16));                  \
        *(uint2*)((char*)AsL + a1) =                                          \
            make_uint2((unsigned)l4 | ((unsigned)l5 << 16),                   \
                       (unsigned)l6 | ((unsigned)l7 << 16));                  \
    } while (0)

    // prologue: panel 0 into buffer 0
    LOADA(0);
    LOADB(0, 0);
    WRITEA(0);          // compiler inserts the vmcnt wait for va0/va1 here
    __syncthreads();    // drains B gload_lds (vmcnt 0) + A ds_writes

    for (int kp = 0; kp < 8; ++kp) {
        const int cur = kp & 1;
        // (a) issue next panel's loads BEFORE compute — latency hides under
        //     the ds_read+MFMA below (A into regs, B direct-to-LDS buf^1)
        if (kp < 7) {
            LOADA(kp + 1);
            LOADB(cur ^ 1, kp + 1);
        }

        // ---- fragment loads (swizzled) + 48 MFMAs on buffer `cur` ----
        bf16x8 ah[4], al[4], bh[4], bl[4];
        const int kb = (lane >> 4) * 16;     // this lane's 8-elem k-chunk (bytes)
        #pragma unroll
        for (int f = 0; f < 4; ++f) {
            const int aaddr = cur * 4096 + sw_addr(f * 16 + (lane & 15), kb);
            ah[f] = *(const bf16x8*)((const char*)AsH + aaddr);
            al[f] = *(const bf16x8*)((const char*)AsL + aaddr);
            const int baddr = cur * 16384 + sw_addr(wn + f * 16 + (lane & 15), kb);
            bh[f] = *(const bf16x8*)((const char*)BsH + baddr);
            bl[f] = *(const bf16x8*)((const char*)BsL + baddr);
        }
        #pragma unroll
        for (int mi = 0; mi < 4; ++mi)
            #pragma unroll
            for (int ni = 0; ni < 4; ++ni) {
                acc[mi][ni] = __builtin_amdgcn_mfma_f32_16x16x32_bf16(
                    ah[mi], bh[ni], acc[mi][ni], 0, 0, 0);
                acc[mi][ni] = __builtin_amdgcn_mfma_f32_16x16x32_bf16(
                    ah[mi], bl[ni], acc[mi][ni], 0, 0, 0);
                acc[mi][ni] = __builtin_amdgcn_mfma_f32_16x16x32_bf16(
                    al[mi], bh[ni], acc[mi][ni], 0, 0, 0);
            }

        // (b) write-late: convert the prefetched A regs into buf^1 AFTER the
        //     MFMAs — by now the loads have landed, the wait is ~free.
        if (kp < 7) WRITEA(cur ^ 1);
        __syncthreads();   // drains next panel's B gload_lds + A ds_writes
    }
#undef LOADA
#undef LOADB
#undef WRITEA

    // ---- epilogue: C/D layout col=lane&15, row=(lane>>4)*4+reg (m89) ----
    #pragma unroll
    for (int mi = 0; mi < 4; ++mi) {
        #pragma unroll
        for (int j = 0; j < 4; ++j) {
            const int m = m0 + mi * 16 + ((lane >> 4) << 2) + j;
            if (m >= M) continue;
            #pragma unroll
            for (int ni = 0; ni < 4; ++ni) {
                const int n = wn + ni * 16 + (lane & 15);
                C[(size_t)m * 256 + n] = acc[mi][ni][j] + bias[n];
            }
        }
    }
}

// ---------------------------------------------------------------------------
// Generic tiled GEMM: C[M,N] = A[M,K] @ B[N,K]^T + bias[N]
// 64x64 tile, 256 threads, 4x4 micro-tile.  (validated rounds 3/5/8/9)
// ---------------------------------------------------------------------------
template<int TM, int TN, int TK>
__global__ __launch_bounds__(256) void gemm_abt_bias(
    const float* __restrict__ A, const float* __restrict__ B,
    const float* __restrict__ bias, float* __restrict__ C,
    int M, int N, int K)
{
    __shared__ float As[TK][TM + 4];
    __shared__ float Bs[TK][TN + 4];
    const int tid = threadIdx.x;
    const int m0 = blockIdx.y * TM;
    const int n0 = blockIdx.x * TN;
    const int tx = tid & 15;
    const int ty = tid >> 4;
    const int ar  = tid >> 2;
    const int ac4 = (tid & 3) << 2;

    float acc[4][4] = {};

    for (int k0 = 0; k0 < K; k0 += TK) {
        {
            const int m = m0 + ar;
            float4 va = make_float4(0.f, 0.f, 0.f, 0.f);
            if (m < M) va = *(const float4*)(A + (size_t)m * K + k0 + ac4);
            As[ac4 + 0][ar] = va.x; As[ac4 + 1][ar] = va.y;
            As[ac4 + 2][ar] = va.z; As[ac4 + 3][ar] = va.w;

            const int n = n0 + ar;
            const float4 vb = *(const float4*)(B + (size_t)n * K + k0 + ac4);
            Bs[ac4 + 0][ar] = vb.x; Bs[ac4 + 1][ar] = vb.y;
            Bs[ac4 + 2][ar] = vb.z; Bs[ac4 + 3][ar] = vb.w;
        }
        __syncthreads();

        #pragma unroll
        for (int k = 0; k < TK; ++k) {
            const float4 a4 = *(const float4*)(&As[k][ty << 2]);
            const float4 b4 = *(const float4*)(&Bs[k][tx << 2]);
            const float a[4] = {a4.x, a4.y, a4.z, a4.w};
            const float b[4] = {b4.x, b4.y, b4.z, b4.w};
            #pragma unroll
            for (int i = 0; i < 4; ++i)
                #pragma unroll
                for (int j = 0; j < 4; ++j)
                    acc[i][j] = fmaf(a[i], b[j], acc[i][j]);
        }
        __syncthreads();
    }

    #pragma unroll
    for (int i = 0; i < 4; ++i) {
        const int m = m0 + (ty << 2) + i;
        if (m >= M) continue;
        #pragma unroll
        for (int j = 0; j < 4; ++j) {
            const int n = n0 + (tx << 2) + j;
            C[(size_t)m * N + n] = acc[i][j] + bias[n];
        }
    }
}

// ---------------------------------------------------------------------------
// Fused query GEMM: C[M,384] = query @ [w_off; w_attn]^T + [b_off; b_attn].
// (validated rounds 5/8/9)
// ---------------------------------------------------------------------------
__global__ __launch_bounds__(256) void gemm_query_fused(
    const float* __restrict__ A,
    const float* __restrict__ Boff,  const float* __restrict__ Battn,
    const float* __restrict__ boff,  const float* __restrict__ battn,
    float* __restrict__ C, int M, int K)
{
    constexpr int TM = 64, TN = 64, TK = 16;
    __shared__ float As[TK][TM + 4];
    __shared__ float Bs[TK][TN + 4];
    const int tid = threadIdx.x;
    const int m0 = blockIdx.y * TM;
    const int n0 = blockIdx.x * TN;
    const bool isAttn = (n0 >= 256);
    const float* __restrict__ B  = isAttn ? Battn : Boff;
    const float* __restrict__ bv = isAttn ? battn : boff;
    const int nbase = isAttn ? (n0 - 256) : n0;

    const int tx = tid & 15;
    const int ty = tid >> 4;
    const int ar  = tid >> 2;
    const int ac4 = (tid & 3) << 2;

    float acc[4][4] = {};

    for (int k0 = 0; k0 < K; k0 += TK) {
        {
            const int m = m0 + ar;
            float4 va = make_float4(0.f, 0.f, 0.f, 0.f);
            if (m < M) va = *(const float4*)(A + (size_t)m * K + k0 + ac4);
            As[ac4 + 0][ar] = va.x; As[ac4 + 1][ar] = va.y;
            As[ac4 + 2][ar] = va.z; As[ac4 + 3][ar] = va.w;

            const float4 vb = *(const float4*)(B + (size_t)(nbase + ar) * K + k0 + ac4);
            Bs[ac4 + 0][ar] = vb.x; Bs[ac4 + 1][ar] = vb.y;
            Bs[ac4 + 2][ar] = vb.z; Bs[ac4 + 3][ar] = vb.w;
        }
        __syncthreads();

        #pragma unroll
        for (int k = 0; k < TK; ++k) {
            const float4 a4 = *(const float4*)(&As[k][ty << 2]);
            const float4 b4 = *(const float4*)(&Bs[k][tx << 2]);
            const float a[4] = {a4.x, a4.y, a4.z, a4.w};
            const float b[4] = {b4.x, b4.y, b4.z, b4.w};
            #pragma unroll
            for (int i = 0; i < 4; ++i)
                #pragma unroll
                for (int j = 0; j < 4; ++j)
                    acc[i][j] = fmaf(a[i], b[j], acc[i][j]);
        }
        __syncthreads();
    }

    #pragma unroll
    for (int i = 0; i < 4; ++i) {
        const int m = m0 + (ty << 2) + i;
        if (m >= M) continue;
        #pragma unroll
        for (int j = 0; j < 4; ++j) {
            const int nl = (tx << 2) + j;
            C[(size_t)m * NQOUT + n0 + nl] = acc[i][j] + bv[nbase + nl];
        }
    }
}

// ---------------------------------------------------------------------------
// Deformable sampling with fused 16-way softmax. (validated rounds 5/8/9)
// ---------------------------------------------------------------------------
__global__ __launch_bounds__(256) void ms_sample_kernel(
    const float* __restrict__ vproj,   // [bs, Lv, 256]
    const float* __restrict__ refp,    // [bs, Lq, 4, 2]
    const float* __restrict__ qout,    // [bs, Lq, 384]
    const int*   __restrict__ shapes,  // [4][2] = (H, W)
    const int*   __restrict__ startix, // [4]
    float* __restrict__ sampled,       // [bs, Lq, 256]
    int Lq, int Lv)
{
    __shared__ float aw_lds[HEADS * LEVELS * POINTS];

    const int bq = blockIdx.x;
    const int b  = bq / Lq;
    const int tid = threadIdx.x;
    const int h = tid >> 5, d = tid & 31;

    const float* vb   = vproj + (size_t)b * Lv * EMBED;
    const float* rowq = qout + (size_t)bq * NQOUT;
    const float* offq = rowq;
    const float* logq = rowq + 256;
    const float* refq = refp + (size_t)bq * LEVELS * 2;

    if (tid < HEADS * LEVELS * POINTS) {
        const float v = logq[tid];
        float m = v;
        #pragma unroll
        for (int s = 8; s > 0; s >>= 1) m = fmaxf(m, __shfl_xor(m, s, 16));
        const float e = __expf(v - m);
        float sum = e;
        #pragma unroll
        for (int s = 8; s > 0; s >>= 1) sum += __shfl_xor(sum, s, 16);
        aw_lds[tid] = e / sum;
    }
    __syncthreads();

    float accv = 0.f;
    #pragma unroll
    for (int l = 0; l < LEVELS; ++l) {
        const int H = shapes[l * 2 + 0];
        const int W = shapes[l * 2 + 1];
        const int st = startix[l];
        const float fW = (float)W, fH = (float)H;
        const float rx = refq[l * 2 + 0];
        const float ry = refq[l * 2 + 1];
        #pragma unroll
        for (int p = 0; p < POINTS; ++p) {
            const int oi = (((h * LEVELS + l) * POINTS) + p) * 2;
            const float ox = offq[oi + 0];
            const float oy = offq[oi + 1];
            const float aw = aw_lds[(h * LEVELS + l) * POINTS + p];
            const float x = (rx + ox / fW) * fW - 0.5f;
            const float y = (ry + oy / fH) * fH - 0.5f;
            const float x0f = floorf(x), y0f = floorf(y);
            const float lx = x - x0f, ly = y - y0f;
            const int x0 = (int)x0f, y0 = (int)y0f;
            float s = 0.f;
            #pragma unroll
            for (int c = 0; c < 4; ++c) {
                const int xi = x0 + (c & 1);
                const int yi = y0 + (c >> 1);
                const float wx = (c & 1) ? lx : 1.f - lx;
                const float wy = (c >> 1) ? ly : 1.f - ly;
                const bool valid = (xi >= 0) && (xi < W) && (yi >= 0) && (yi < H);
                const int xc = min(max(xi, 0), W - 1);
                const int yc = min(max(yi, 0), H - 1);
                const float val = vb[(size_t)(st + yc * W + xc) * EMBED + (h << 5) + d];
                s = fmaf(valid ? wx * wy : 0.f, val, s);
            }
            accv = fmaf(aw, s, accv);
        }
    }
    sampled[(size_t)bq * EMBED + tid] = accv;
}

// ---------------------------------------------------------------------------
extern "C" void kernel_launch(void* const* d_in, const int* in_sizes, int n_in,
                              void* d_out, int out_size, void* d_ws, size_t ws_size,
                              hipStream_t stream)
{
    const float* query   = (const float*)d_in[0];
    const float* refp    = (const float*)d_in[1];
    const float* value   = (const float*)d_in[2];
    const int*   shapes  = (const int*)d_in[3];
    const int*   startix = (const int*)d_in[4];
    const float* w_value = (const float*)d_in[5];
    const float* b_value = (const float*)d_in[6];
    const float* w_off   = (const float*)d_in[7];
    const float* b_off   = (const float*)d_in[8];
    const float* w_attn  = (const float*)d_in[9];
    const float* b_attn  = (const float*)d_in[10];
    const float* w_out   = (const float*)d_in[11];
    const float* b_out   = (const float*)d_in[12];
    float* out = (float*)d_out;

    const int bs = 4;
    const int Lq = in_sizes[0] / (bs * EMBED);   // 900
    const int Lv = in_sizes[2] / (bs * EMBED);   // 13294
    const int BQ = bs * Lq;                      // 3600
    const int M  = bs * Lv;                      // 53176

    float* ws = (float*)d_ws;
    float* vproj   = ws; ws += (size_t)bs * Lv * EMBED;   // 54.5 MB
    float* qoutb   = ws; ws += (size_t)BQ * NQOUT;        // 5.5 MB
    float* sampled = ws; ws += (size_t)BQ * EMBED;        // 3.7 MB
    unsigned short* bhi = (unsigned short*)ws;            // 128 KB
    unsigned short* blo = bhi + 256 * 256;                // 128 KB

    // 0. prep: weight -> swizzled hi/lo bf16 LDS images
    hipLaunchKernelGGL(prep_w, dim3(8), dim3(256), 0, stream, w_value, bhi, blo);

    // 1. value projection via bf16-split MFMA (T14 async-STAGE split)
    hipLaunchKernelGGL(vproj_mfma, dim3((M + 63) / 64), dim3(256), 0, stream,
                       value, bhi, blo, b_value, vproj, M);

    // 2. fused query GEMM: offsets (N=256) + attn logits (N=128)
    {
        dim3 grid(NQOUT / 64, (BQ + 63) / 64);
        hipLaunchKernelGGL(gemm_query_fused, grid, dim3(256), 0, stream,
                           query, w_off, w_attn, b_off, b_attn, qoutb, BQ, EMBED);
    }
    // 3. deformable sampling with fused softmax
    hipLaunchKernelGGL(ms_sample_kernel, dim3(BQ), dim3(256), 0, stream,
                       vproj, refp, qoutb, shapes, startix, sampled, Lq, Lv);

    // 4. output projection: [BQ,256] @ w_out.T -> d_out
    {
        dim3 grid(EMBED / 64, (BQ + 63) / 64);
        hipLaunchKernelGGL((gemm_abt_bias<64, 64, 16>), grid, dim3(256), 0, stream,
                           sampled, w_out, b_out, out, BQ, EMBED, EMBED);
    }
}